// Round 1
// baseline (1336.332 us; speedup 1.0000x reference)
//
#include <hip/hip_runtime.h>
#include <hip/hip_bf16.h>
#include <cstdint>

// Problem constants
#define B_   2
#define S_   512
#define N_   20000
#define D_   384
#define H_   3
#define C_   128
#define E_   320000
#define DG_  128
#define BN_  (B_ * N_)            // 40000
#define F_   (H_ * C_)            // 384
#define ETOT_ (B_ * E_ + BN_)     // 680000

#define TS 64
#define KT 16
#define KSPLIT 10
#define KCH (N_ / KSPLIT)         // 2000

// ---------------- shared GEMM inner product (4x4 per thread) ----------------
__device__ __forceinline__ void mm_inner(const float As[KT][TS + 4],
                                         const float Bs[KT][TS + 4],
                                         int tm, int tn, float acc[4][4]) {
#pragma unroll
  for (int k = 0; k < KT; ++k) {
    float4 a = *(const float4*)&As[k][tm];
    float4 v = *(const float4*)&Bs[k][tn];
    acc[0][0] = fmaf(a.x, v.x, acc[0][0]); acc[0][1] = fmaf(a.x, v.y, acc[0][1]);
    acc[0][2] = fmaf(a.x, v.z, acc[0][2]); acc[0][3] = fmaf(a.x, v.w, acc[0][3]);
    acc[1][0] = fmaf(a.y, v.x, acc[1][0]); acc[1][1] = fmaf(a.y, v.y, acc[1][1]);
    acc[1][2] = fmaf(a.y, v.z, acc[1][2]); acc[1][3] = fmaf(a.y, v.w, acc[1][3]);
    acc[2][0] = fmaf(a.z, v.x, acc[2][0]); acc[2][1] = fmaf(a.z, v.y, acc[2][1]);
    acc[2][2] = fmaf(a.z, v.z, acc[2][2]); acc[2][3] = fmaf(a.z, v.w, acc[2][3]);
    acc[3][0] = fmaf(a.w, v.x, acc[3][0]); acc[3][1] = fmaf(a.w, v.y, acc[3][1]);
    acc[3][2] = fmaf(a.w, v.z, acc[3][2]); acc[3][3] = fmaf(a.w, v.w, acc[3][3]);
  }
}

// ---------------- GEMM 1: x[b,n,d] = sum_s Wq[n,s]*xe[b,s,d] + bq[n] + mask*Wm + bm
__global__ __launch_bounds__(256) void gemm_q_kernel(
    const float* __restrict__ Wq, const float* __restrict__ xe,
    const float* __restrict__ bq, const float* __restrict__ mask,
    const float* __restrict__ Wm, const float* __restrict__ bm,
    float* __restrict__ xout) {
  int b  = blockIdx.z;
  int m0 = blockIdx.x * TS;
  int n0 = blockIdx.y * TS;
  const float* Bp = xe + (size_t)b * S_ * D_;
  __shared__ float As[KT][TS + 4];
  __shared__ float Bs[KT][TS + 4];
  int tid = threadIdx.x;
  int tm = (tid & 15) * 4, tn = (tid >> 4) * 4;
  int arow = tid >> 2, acol = (tid & 3) * 4;
  int brow = tid >> 4, bcol = (tid & 15) * 4;
  float acc[4][4] = {};
  int gr = m0 + arow;
  const float4 z4 = make_float4(0.f, 0.f, 0.f, 0.f);
  for (int k0 = 0; k0 < S_; k0 += KT) {
    float4 av = (gr < N_) ? *(const float4*)(Wq + (size_t)gr * S_ + (k0 + acol)) : z4;
    float4 bv = *(const float4*)(Bp + (size_t)(k0 + brow) * D_ + (n0 + bcol));
    __syncthreads();
    As[acol + 0][arow] = av.x; As[acol + 1][arow] = av.y;
    As[acol + 2][arow] = av.z; As[acol + 3][arow] = av.w;
    *(float4*)&Bs[brow][bcol] = bv;
    __syncthreads();
    mm_inner(As, Bs, tm, tn, acc);
  }
#pragma unroll
  for (int i = 0; i < 4; ++i) {
    int row = m0 + tm + i;
    if (row < N_) {
      int cb = n0 + tn;
      float bqv = bq[row];
      float mk  = mask[b * N_ + row];
      float4 wmv = *(const float4*)(Wm + cb);
      float4 bmv = *(const float4*)(bm + cb);
      float4 o;
      o.x = acc[i][0] + bqv + mk * wmv.x + bmv.x;
      o.y = acc[i][1] + bqv + mk * wmv.y + bmv.y;
      o.z = acc[i][2] + bqv + mk * wmv.z + bmv.z;
      o.w = acc[i][3] + bqv + mk * wmv.w + bmv.w;
      *(float4*)(xout + ((size_t)(b * N_ + row)) * D_ + cb) = o;
    }
  }
}

// ---------------- GEMM 2: xp[i,f] = sum_d x[i,d] * Wlin[f,d]  (NT)
__global__ __launch_bounds__(256) void gemm_lin_kernel(
    const float* __restrict__ x, const float* __restrict__ Wlin,
    float* __restrict__ xp) {
  int m0 = blockIdx.x * TS;
  int n0 = blockIdx.y * TS;
  __shared__ float As[KT][TS + 4];
  __shared__ float Bs[KT][TS + 4];
  int tid = threadIdx.x;
  int tm = (tid & 15) * 4, tn = (tid >> 4) * 4;
  int lrow = tid >> 2, lcol = (tid & 3) * 4;
  float acc[4][4] = {};
  int gr = m0 + lrow;
  const float4 z4 = make_float4(0.f, 0.f, 0.f, 0.f);
  for (int k0 = 0; k0 < D_; k0 += KT) {
    float4 av = (gr < BN_) ? *(const float4*)(x + (size_t)gr * D_ + k0 + lcol) : z4;
    float4 bv = *(const float4*)(Wlin + (size_t)(n0 + lrow) * D_ + k0 + lcol);
    __syncthreads();
    As[lcol + 0][lrow] = av.x; As[lcol + 1][lrow] = av.y;
    As[lcol + 2][lrow] = av.z; As[lcol + 3][lrow] = av.w;
    Bs[lcol + 0][lrow] = bv.x; Bs[lcol + 1][lrow] = bv.y;
    Bs[lcol + 2][lrow] = bv.z; Bs[lcol + 3][lrow] = bv.w;
    __syncthreads();
    mm_inner(As, Bs, tm, tn, acc);
  }
#pragma unroll
  for (int i = 0; i < 4; ++i) {
    int row = m0 + tm + i;
    if (row < BN_) {
      float4 o = make_float4(acc[i][0], acc[i][1], acc[i][2], acc[i][3]);
      *(float4*)(xp + (size_t)row * F_ + n0 + tn) = o;
    }
  }
}

// ---------------- attention coefficients: a_src/a_dst[i,h] = dot(xp[i,h,:], att[h,:])
__global__ __launch_bounds__(256) void att_kernel(
    const float* __restrict__ xp, const float* __restrict__ att_src,
    const float* __restrict__ att_dst, float* __restrict__ a_src,
    float* __restrict__ a_dst) {
  int gid = blockIdx.x * blockDim.x + threadIdx.x;
  int wid = gid >> 6;
  int lane = threadIdx.x & 63;
  if (wid >= BN_ * H_) return;
  int i = wid / H_, h = wid - i * H_;
  const float* row = xp + (size_t)i * F_ + h * C_;
  const float* as = att_src + h * C_;
  const float* ad = att_dst + h * C_;
  float v0 = row[lane], v1 = row[lane + 64];
  float s1 = v0 * as[lane] + v1 * as[lane + 64];
  float s2 = v0 * ad[lane] + v1 * ad[lane + 64];
#pragma unroll
  for (int off = 32; off > 0; off >>= 1) {
    s1 += __shfl_down(s1, off);
    s2 += __shfl_down(s2, off);
  }
  if (lane == 0) {
    a_src[i * H_ + h] = s1;
    a_dst[i * H_ + h] = s2;
  }
}

// ---------------- CSR build ----------------
__global__ __launch_bounds__(256) void count_kernel(const int* __restrict__ ei,
                                                    int* __restrict__ counts) {
  int idx = blockIdx.x * blockDim.x + threadIdx.x;
  if (idx >= 2 * E_) return;
  int b = (idx >= E_) ? 1 : 0;
  int e = idx - b * E_;
  int d = ei[E_ + e];
  atomicAdd(&counts[b * N_ + d], 1);
}

__global__ __launch_bounds__(1024) void scan_kernel(const int* __restrict__ counts,
                                                    int* __restrict__ offs,
                                                    int* __restrict__ cursor) {
  __shared__ int sdata[1024];
  __shared__ int running_s;
  int t = threadIdx.x;
  if (t == 0) running_s = 0;
  __syncthreads();
  for (int base = 0; base < BN_; base += 1024) {
    int i = base + t;
    int v = (i < BN_) ? (counts[i] + 1) : 0;  // +1 = self loop
    int runbase = running_s;
    __syncthreads();
    sdata[t] = v;
    __syncthreads();
    int val = v;
    for (int o = 1; o < 1024; o <<= 1) {
      int add = (t >= o) ? sdata[t - o] : 0;
      __syncthreads();
      val += add;
      sdata[t] = val;
      __syncthreads();
    }
    int excl = val - v;
    if (i < BN_) { offs[i] = runbase + excl; cursor[i] = runbase + excl; }
    int total = sdata[1023];
    __syncthreads();
    if (t == 0) running_s = runbase + total;
    __syncthreads();
  }
}

__global__ __launch_bounds__(256) void fill_kernel(const int* __restrict__ ei,
                                                   int* __restrict__ cursor,
                                                   int* __restrict__ col) {
  int idx = blockIdx.x * blockDim.x + threadIdx.x;
  if (idx >= ETOT_) return;
  if (idx < 2 * E_) {
    int b = (idx >= E_) ? 1 : 0;
    int e = idx - b * E_;
    int s = ei[e];
    int d = ei[E_ + e];
    int pos = atomicAdd(&cursor[b * N_ + d], 1);
    col[pos] = b * N_ + s;
  } else {
    int i = idx - 2 * E_;
    int pos = atomicAdd(&cursor[i], 1);
    col[pos] = i;
  }
}

// ---------------- segment softmax + aggregation: one block per dst node
__global__ __launch_bounds__(384) void agg_kernel(
    const int* __restrict__ offs, const int* __restrict__ ends,
    const int* __restrict__ col, const float* __restrict__ a_src,
    const float* __restrict__ a_dst, const float* __restrict__ xp,
    const float* __restrict__ bias_gat, float* __restrict__ out) {
  int i = blockIdx.x;
  int t = threadIdx.x;
  int h = t >> 7;        // head (C=128)
  int c = t & 127;
  int beg = offs[i];
  int nE = ends[i] - beg;
  float adh = a_dst[i * H_ + h];
  __shared__ float red[384];

  // phase A: per-head max over incoming edges
  float m = -1e30f;
  for (int j = c; j < nE; j += 128) {
    int s = col[beg + j];
    float e = a_src[s * H_ + h] + adh;
    e = (e > 0.f) ? e : 0.2f * e;
    m = fmaxf(m, e);
  }
  red[t] = m;
  __syncthreads();
#pragma unroll
  for (int o = 64; o > 0; o >>= 1) {
    if (c < o) red[t] = fmaxf(red[t], red[t + o]);
    __syncthreads();
  }
  float mh = red[h * 128];
  __syncthreads();

  // phase B: per-head denom
  float ssum = 0.f;
  for (int j = c; j < nE; j += 128) {
    int s = col[beg + j];
    float e = a_src[s * H_ + h] + adh;
    e = (e > 0.f) ? e : 0.2f * e;
    ssum += __expf(e - mh);
  }
  red[t] = ssum;
  __syncthreads();
#pragma unroll
  for (int o = 64; o > 0; o >>= 1) {
    if (c < o) red[t] += red[t + o];
    __syncthreads();
  }
  float rden = 1.0f / red[h * 128];
  __syncthreads();

  // phase C: weighted aggregation; thread t owns feature t of out[i]
  float acc = 0.f;
  for (int j = 0; j < nE; ++j) {
    int s = col[beg + j];
    float e = a_src[s * H_ + h] + adh;
    e = (e > 0.f) ? e : 0.2f * e;
    float alpha = __expf(e - mh) * rden;
    acc = fmaf(alpha, xp[(size_t)s * F_ + t], acc);
  }
  out[(size_t)i * F_ + t] = acc + bias_gat[t];
}

// ---------------- GEMM 3 (split-K): P[b,s,f] += sum_n Wproj[s,n]*gout[b,n,f]
__global__ __launch_bounds__(256) void gemm_proj_kernel(
    const float* __restrict__ Wproj, const float* __restrict__ gout,
    float* __restrict__ P) {
  int bz = blockIdx.z;
  int b = bz / KSPLIT, ks = bz - b * KSPLIT;
  int m0 = blockIdx.x * TS;   // s
  int n0 = blockIdx.y * TS;   // f
  const float* Bp = gout + (size_t)b * N_ * F_;
  int kbeg = ks * KCH;
  __shared__ float As[KT][TS + 4];
  __shared__ float Bs[KT][TS + 4];
  int tid = threadIdx.x;
  int tm = (tid & 15) * 4, tn = (tid >> 4) * 4;
  int arow = tid >> 2, acol = (tid & 3) * 4;
  int brow = tid >> 4, bcol = (tid & 15) * 4;
  float acc[4][4] = {};
  for (int k0 = kbeg; k0 < kbeg + KCH; k0 += KT) {
    float4 av = *(const float4*)(Wproj + (size_t)(m0 + arow) * N_ + (k0 + acol));
    float4 bv = *(const float4*)(Bp + (size_t)(k0 + brow) * F_ + (n0 + bcol));
    __syncthreads();
    As[acol + 0][arow] = av.x; As[acol + 1][arow] = av.y;
    As[acol + 2][arow] = av.z; As[acol + 3][arow] = av.w;
    *(float4*)&Bs[brow][bcol] = bv;
    __syncthreads();
    mm_inner(As, Bs, tm, tn, acc);
  }
#pragma unroll
  for (int i = 0; i < 4; ++i) {
    int row = m0 + tm + i;
#pragma unroll
    for (int j = 0; j < 4; ++j) {
      atomicAdd(&P[((size_t)b * S_ + row) * F_ + n0 + tn + j], acc[i][j]);
    }
  }
}

// ---------------- GEMM 4: final[b,s,g] = sum_f (P[b,s,f]+bproj[s])*Wtemp[g,f] + btemp[g]
__global__ __launch_bounds__(128) void temp_kernel(
    const float* __restrict__ P, const float* __restrict__ bproj,
    const float* __restrict__ Wtemp, const float* __restrict__ btemp,
    float* __restrict__ out) {
  int bs = blockIdx.x;          // 0..B*S-1
  int s = bs & (S_ - 1);
  int g = threadIdx.x;
  __shared__ float prow[F_];
  float bp = bproj[s];
  for (int f = g; f < F_; f += 128) prow[f] = P[(size_t)bs * F_ + f] + bp;
  __syncthreads();
  float acc = btemp[g];
  const float* w = Wtemp + (size_t)g * F_;
  for (int f = 0; f < F_; f += 4) {
    float4 pv = *(const float4*)&prow[f];
    float4 wv = *(const float4*)&w[f];
    acc += pv.x * wv.x + pv.y * wv.y + pv.z * wv.z + pv.w * wv.w;
  }
  out[(size_t)bs * DG_ + g] = acc;
}

// ---------------- launcher ----------------
extern "C" void kernel_launch(void* const* d_in, const int* in_sizes, int n_in,
                              void* d_out, int out_size, void* d_ws, size_t ws_size,
                              hipStream_t stream) {
  const float* x_enc   = (const float*)d_in[0];
  const float* mask    = (const float*)d_in[1];
  const int*   ei      = (const int*)d_in[2];
  const float* Wq      = (const float*)d_in[3];
  const float* bq      = (const float*)d_in[4];
  const float* Wm      = (const float*)d_in[5];
  const float* bm      = (const float*)d_in[6];
  const float* Wlin    = (const float*)d_in[7];
  const float* att_src = (const float*)d_in[8];
  const float* att_dst = (const float*)d_in[9];
  const float* bias_gat= (const float*)d_in[10];
  const float* Wproj   = (const float*)d_in[11];
  const float* bproj   = (const float*)d_in[12];
  const float* Wtemp   = (const float*)d_in[13];
  const float* btemp   = (const float*)d_in[14];
  float* outp = (float*)d_out;

  char* ws = (char*)d_ws;
  size_t off = 0;
  auto alloc = [&](size_t bytes) {
    char* p = ws + off;
    off = (off + bytes + 255) & ~(size_t)255;
    return p;
  };
  float* xbuf  = (float*)alloc((size_t)BN_ * F_ * 4);  // x, later reused as GAT out
  float* xp    = (float*)alloc((size_t)BN_ * F_ * 4);
  float* a_src = (float*)alloc((size_t)BN_ * H_ * 4);
  float* a_dst = (float*)alloc((size_t)BN_ * H_ * 4);
  int* counts  = (int*)alloc((size_t)BN_ * 4);
  int* offs    = (int*)alloc((size_t)BN_ * 4);
  int* cursor  = (int*)alloc((size_t)BN_ * 4);
  int* col     = (int*)alloc((size_t)ETOT_ * 4);
  float* P     = (float*)alloc((size_t)B_ * S_ * F_ * 4);
  if (off > ws_size) return;  // workspace too small: fail loudly via absmax

  hipMemsetAsync(counts, 0, (size_t)BN_ * 4, stream);
  hipMemsetAsync(P, 0, (size_t)B_ * S_ * F_ * 4, stream);

  gemm_q_kernel<<<dim3((N_ + TS - 1) / TS, D_ / TS, B_), 256, 0, stream>>>(
      Wq, x_enc, bq, mask, Wm, bm, xbuf);
  gemm_lin_kernel<<<dim3(BN_ / TS, F_ / TS, 1), 256, 0, stream>>>(xbuf, Wlin, xp);
  att_kernel<<<(BN_ * H_ + 3) / 4, 256, 0, stream>>>(xp, att_src, att_dst, a_src, a_dst);
  count_kernel<<<(2 * E_ + 255) / 256, 256, 0, stream>>>(ei, counts);
  scan_kernel<<<1, 1024, 0, stream>>>(counts, offs, cursor);
  fill_kernel<<<(ETOT_ + 255) / 256, 256, 0, stream>>>(ei, cursor, col);
  agg_kernel<<<BN_, 384, 0, stream>>>(offs, cursor, col, a_src, a_dst, xp, bias_gat, xbuf);
  gemm_proj_kernel<<<dim3(S_ / TS, F_ / TS, B_ * KSPLIT), 256, 0, stream>>>(Wproj, xbuf, P);
  temp_kernel<<<B_ * S_, 128, 0, stream>>>(P, bproj, Wtemp, btemp, outp);
}

// Round 2
// 838.344 us; speedup vs baseline: 1.5940x; 1.5940x over previous
//
#include <hip/hip_runtime.h>
#include <hip/hip_bf16.h>
#include <cstdint>

// Problem constants
#define B_   2
#define S_   512
#define N_   20000
#define D_   384
#define H_   3
#define C_   128
#define E_   320000
#define DG_  128
#define BN_  (B_ * N_)            // 40000
#define F_   (H_ * C_)            // 384
#define ETOT_ (B_ * E_ + BN_)     // 680000

#define MPADQ 20096               // N_ padded to 128
#define MPADL 40064               // BN_ padded to 128

#define TS 64
#define KT 16
#define KSPLIT 10
#define KCH (N_ / KSPLIT)         // 2000

using short8  = __attribute__((ext_vector_type(8))) short;
using floatx4 = __attribute__((ext_vector_type(4))) float;

// ================= conversion kernels =================
struct bf4 { __hip_bfloat16 a, b, c, d; };

__global__ __launch_bounds__(256) void conv_wq_kernel(const float* __restrict__ Wq,
                                                      __hip_bfloat16* __restrict__ o) {
  int idx = blockIdx.x * 256 + threadIdx.x;   // over MPADQ*512/4
  if (idx >= (MPADQ * 512) / 4) return;
  int e = idx * 4;
  int row = e >> 9;
  float4 v = make_float4(0.f, 0.f, 0.f, 0.f);
  if (row < N_) v = *(const float4*)(Wq + e);
  bf4 r{__float2bfloat16(v.x), __float2bfloat16(v.y),
        __float2bfloat16(v.z), __float2bfloat16(v.w)};
  *(bf4*)(o + e) = r;
}

// xe [B][S][D] fp32 -> xeT [B][D][S] bf16
__global__ __launch_bounds__(256) void conv_xeT_kernel(const float* __restrict__ xe,
                                                       __hip_bfloat16* __restrict__ o) {
  int idx = blockIdx.x * 256 + threadIdx.x;
  if (idx >= B_ * S_ * D_) return;
  int s = idx & 511;
  int rest = idx >> 9;
  int d = rest % D_;
  int b = rest / D_;
  o[idx] = __float2bfloat16(xe[(size_t)b * S_ * D_ + (size_t)s * D_ + d]);
}

__global__ __launch_bounds__(256) void conv_wlin_kernel(const float* __restrict__ W,
                                                        __hip_bfloat16* __restrict__ o) {
  int idx = blockIdx.x * 256 + threadIdx.x;   // over 384*384/4
  if (idx >= (F_ * D_) / 4) return;
  int e = idx * 4;
  float4 v = *(const float4*)(W + e);
  bf4 r{__float2bfloat16(v.x), __float2bfloat16(v.y),
        __float2bfloat16(v.z), __float2bfloat16(v.w)};
  *(bf4*)(o + e) = r;
}

// ================= bf16 MFMA GEMM (NT: A[m][k], Bt[n][k], both k-major) =================
// block tile 128x128, BK=32, 256 threads = 4 waves, wave tile 64x64 (4x4 of 16x16x32)
template <int EPI>
__global__ __launch_bounds__(256) void mfma_gemm_nt(
    const __hip_bfloat16* __restrict__ A, const __hip_bfloat16* __restrict__ Bt,
    __hip_bfloat16* __restrict__ Cout, int K, int Mvalid,
    size_t bstrideB, size_t bstrideC,
    const float* __restrict__ bq, const float* __restrict__ mask,
    const float* __restrict__ Wm, const float* __restrict__ bm) {
  const int tid = threadIdx.x;
  const int m0 = blockIdx.x * 128;
  const int n0 = blockIdx.y * 128;
  const int bz = blockIdx.z;

  const unsigned short* Ap = (const unsigned short*)A;
  const unsigned short* Bp = (const unsigned short*)(Bt + bstrideB * bz);

  __shared__ __align__(16) unsigned short As[128][40];
  __shared__ __align__(16) unsigned short Bs[128][40];

  const int wave = tid >> 6, lane = tid & 63;
  const int wm = (wave & 1) * 64, wn = (wave >> 1) * 64;
  const int lrow = lane & 15, lk = (lane >> 4) * 8;

  const int srow = tid >> 2;            // 0..63
  const int skoff = (tid & 3) * 8;      // 0,8,16,24

  floatx4 acc[4][4];
#pragma unroll
  for (int i = 0; i < 4; ++i)
#pragma unroll
    for (int j = 0; j < 4; ++j) acc[i][j] = floatx4{0.f, 0.f, 0.f, 0.f};

  for (int k0 = 0; k0 < K; k0 += 32) {
    int4 av0 = *(const int4*)(Ap + (size_t)(m0 + srow) * K + k0 + skoff);
    int4 av1 = *(const int4*)(Ap + (size_t)(m0 + 64 + srow) * K + k0 + skoff);
    int4 bv0 = *(const int4*)(Bp + (size_t)(n0 + srow) * K + k0 + skoff);
    int4 bv1 = *(const int4*)(Bp + (size_t)(n0 + 64 + srow) * K + k0 + skoff);
    __syncthreads();
    *(int4*)&As[srow][skoff] = av0;
    *(int4*)&As[64 + srow][skoff] = av1;
    *(int4*)&Bs[srow][skoff] = bv0;
    *(int4*)&Bs[64 + srow][skoff] = bv1;
    __syncthreads();
    short8 af[4], bf[4];
#pragma unroll
    for (int mt = 0; mt < 4; ++mt)
      af[mt] = *(const short8*)&As[wm + mt * 16 + lrow][lk];
#pragma unroll
    for (int nt = 0; nt < 4; ++nt)
      bf[nt] = *(const short8*)&Bs[wn + nt * 16 + lrow][lk];
#pragma unroll
    for (int mt = 0; mt < 4; ++mt)
#pragma unroll
      for (int nt = 0; nt < 4; ++nt)
        acc[mt][nt] = __builtin_amdgcn_mfma_f32_16x16x32_bf16(af[mt], bf[nt],
                                                              acc[mt][nt], 0, 0, 0);
  }

  // epilogue: C/D layout col=lane&15, row=(lane>>4)*4+r
  __hip_bfloat16* Cb = Cout + bstrideC * bz;
#pragma unroll
  for (int mt = 0; mt < 4; ++mt) {
#pragma unroll
    for (int r = 0; r < 4; ++r) {
      int rg = m0 + wm + mt * 16 + (lane >> 4) * 4 + r;
      if (rg < Mvalid) {
        float bqv = 0.f, mkv = 0.f;
        if (EPI) {
          bqv = bq[rg];
          mkv = mask[bz * N_ + rg];
        }
#pragma unroll
        for (int nt = 0; nt < 4; ++nt) {
          int cg = n0 + wn + nt * 16 + lrow;
          float v = acc[mt][nt][r];
          if (EPI) v += bqv + mkv * Wm[cg] + bm[cg];
          Cb[(size_t)rg * F_ + cg] = __float2bfloat16(v);
        }
      }
    }
  }
}

// ---------------- attention coefficients ----------------
__global__ __launch_bounds__(256) void att_kernel(
    const __hip_bfloat16* __restrict__ xp, const float* __restrict__ att_src,
    const float* __restrict__ att_dst, float* __restrict__ a_src,
    float* __restrict__ a_dst) {
  int gid = blockIdx.x * blockDim.x + threadIdx.x;
  int wid = gid >> 6;
  int lane = threadIdx.x & 63;
  if (wid >= BN_ * H_) return;
  int i = wid / H_, h = wid - i * H_;
  const __hip_bfloat16* row = xp + (size_t)i * F_ + h * C_;
  const float* as = att_src + h * C_;
  const float* ad = att_dst + h * C_;
  float v0 = __bfloat162float(row[lane]), v1 = __bfloat162float(row[lane + 64]);
  float s1 = v0 * as[lane] + v1 * as[lane + 64];
  float s2 = v0 * ad[lane] + v1 * ad[lane + 64];
#pragma unroll
  for (int off = 32; off > 0; off >>= 1) {
    s1 += __shfl_down(s1, off);
    s2 += __shfl_down(s2, off);
  }
  if (lane == 0) {
    a_src[i * H_ + h] = s1;
    a_dst[i * H_ + h] = s2;
  }
}

// ---------------- CSR build ----------------
__global__ __launch_bounds__(256) void count_kernel(const int* __restrict__ ei,
                                                    int* __restrict__ counts) {
  int idx = blockIdx.x * blockDim.x + threadIdx.x;
  if (idx >= 2 * E_) return;
  int b = (idx >= E_) ? 1 : 0;
  int e = idx - b * E_;
  int d = ei[E_ + e];
  atomicAdd(&counts[b * N_ + d], 1);
}

__global__ __launch_bounds__(1024) void scan_kernel(const int* __restrict__ counts,
                                                    int* __restrict__ offs,
                                                    int* __restrict__ cursor) {
  __shared__ int sdata[1024];
  __shared__ int running_s;
  int t = threadIdx.x;
  if (t == 0) running_s = 0;
  __syncthreads();
  for (int base = 0; base < BN_; base += 1024) {
    int i = base + t;
    int v = (i < BN_) ? (counts[i] + 1) : 0;  // +1 = self loop
    int runbase = running_s;
    __syncthreads();
    sdata[t] = v;
    __syncthreads();
    int val = v;
    for (int o = 1; o < 1024; o <<= 1) {
      int add = (t >= o) ? sdata[t - o] : 0;
      __syncthreads();
      val += add;
      sdata[t] = val;
      __syncthreads();
    }
    int excl = val - v;
    if (i < BN_) { offs[i] = runbase + excl; cursor[i] = runbase + excl; }
    int total = sdata[1023];
    __syncthreads();
    if (t == 0) running_s = runbase + total;
    __syncthreads();
  }
}

__global__ __launch_bounds__(256) void fill_kernel(const int* __restrict__ ei,
                                                   int* __restrict__ cursor,
                                                   int* __restrict__ col) {
  int idx = blockIdx.x * blockDim.x + threadIdx.x;
  if (idx >= ETOT_) return;
  if (idx < 2 * E_) {
    int b = (idx >= E_) ? 1 : 0;
    int e = idx - b * E_;
    int s = ei[e];
    int d = ei[E_ + e];
    int pos = atomicAdd(&cursor[b * N_ + d], 1);
    col[pos] = b * N_ + s;
  } else {
    int i = idx - 2 * E_;
    int pos = atomicAdd(&cursor[i], 1);
    col[pos] = i;
  }
}

// ---------------- segment softmax + aggregation ----------------
#define CHK 128
__global__ __launch_bounds__(384) void agg_kernel(
    const int* __restrict__ offs, const int* __restrict__ ends,
    const int* __restrict__ col, const float* __restrict__ a_src,
    const float* __restrict__ a_dst, const __hip_bfloat16* __restrict__ xp,
    const float* __restrict__ bias_gat, float* __restrict__ out) {
  int i = blockIdx.x;
  int t = threadIdx.x;
  int h = t >> 7;        // head (C=128)
  int c = t & 127;
  int beg = offs[i];
  int nE = ends[i] - beg;
  __shared__ float red[384];
  __shared__ float sm[H_], sr[H_], sad[H_];
  __shared__ int scol[CHK];
  __shared__ float salpha[CHK][H_];
  if (t < H_) sad[t] = a_dst[i * H_ + t];
  float adh = a_dst[i * H_ + h];

  // phase A: per-head max
  float m = -1e30f;
  for (int j = c; j < nE; j += 128) {
    int s = col[beg + j];
    float e = a_src[s * H_ + h] + adh;
    e = (e > 0.f) ? e : 0.2f * e;
    m = fmaxf(m, e);
  }
  red[t] = m;
  __syncthreads();
#pragma unroll
  for (int o = 64; o > 0; o >>= 1) {
    if (c < o) red[t] = fmaxf(red[t], red[t + o]);
    __syncthreads();
  }
  float mh = red[h * 128];
  if (c == 0) sm[h] = mh;
  __syncthreads();

  // phase B: per-head denom
  float ssum = 0.f;
  for (int j = c; j < nE; j += 128) {
    int s = col[beg + j];
    float e = a_src[s * H_ + h] + adh;
    e = (e > 0.f) ? e : 0.2f * e;
    ssum += __expf(e - mh);
  }
  red[t] = ssum;
  __syncthreads();
#pragma unroll
  for (int o = 64; o > 0; o >>= 1) {
    if (c < o) red[t] += red[t + o];
    __syncthreads();
  }
  if (c == 0) sr[h] = 1.0f / red[h * 128];

  // phase C: chunked — stage col + alpha in LDS, then gather bf16 xp
  float acc = 0.f;
  for (int c0 = 0; c0 < nE; c0 += CHK) {
    int cn = min(CHK, nE - c0);
    __syncthreads();
    if (t < cn) {
      int s = col[beg + c0 + t];
      scol[t] = s;
#pragma unroll
      for (int hh = 0; hh < H_; ++hh) {
        float e = a_src[s * H_ + hh] + sad[hh];
        e = (e > 0.f) ? e : 0.2f * e;
        salpha[t][hh] = __expf(e - sm[hh]) * sr[hh];
      }
    }
    __syncthreads();
#pragma unroll 4
    for (int j = 0; j < cn; ++j) {
      int s = scol[j];
      acc = fmaf(salpha[j][h], __bfloat162float(xp[(size_t)s * F_ + t]), acc);
    }
  }
  out[(size_t)i * F_ + t] = acc + bias_gat[t];
}

// ---------------- fp32 GEMM inner (kept for gemm_proj) ----------------
__device__ __forceinline__ void mm_inner(const float As[KT][TS + 4],
                                         const float Bs[KT][TS + 4],
                                         int tm, int tn, float acc[4][4]) {
#pragma unroll
  for (int k = 0; k < KT; ++k) {
    float4 a = *(const float4*)&As[k][tm];
    float4 v = *(const float4*)&Bs[k][tn];
    acc[0][0] = fmaf(a.x, v.x, acc[0][0]); acc[0][1] = fmaf(a.x, v.y, acc[0][1]);
    acc[0][2] = fmaf(a.x, v.z, acc[0][2]); acc[0][3] = fmaf(a.x, v.w, acc[0][3]);
    acc[1][0] = fmaf(a.y, v.x, acc[1][0]); acc[1][1] = fmaf(a.y, v.y, acc[1][1]);
    acc[1][2] = fmaf(a.y, v.z, acc[1][2]); acc[1][3] = fmaf(a.y, v.w, acc[1][3]);
    acc[2][0] = fmaf(a.z, v.x, acc[2][0]); acc[2][1] = fmaf(a.z, v.y, acc[2][1]);
    acc[2][2] = fmaf(a.z, v.z, acc[2][2]); acc[2][3] = fmaf(a.z, v.w, acc[2][3]);
    acc[3][0] = fmaf(a.w, v.x, acc[3][0]); acc[3][1] = fmaf(a.w, v.y, acc[3][1]);
    acc[3][2] = fmaf(a.w, v.z, acc[3][2]); acc[3][3] = fmaf(a.w, v.w, acc[3][3]);
  }
}

// ---------------- GEMM 3 (split-K, fp32): P[b,s,f] += sum_n Wproj[s,n]*gat[b,n,f]
__global__ __launch_bounds__(256) void gemm_proj_kernel(
    const float* __restrict__ Wproj, const float* __restrict__ gout,
    float* __restrict__ P) {
  int bz = blockIdx.z;
  int b = bz / KSPLIT, ks = bz - b * KSPLIT;
  int m0 = blockIdx.x * TS;   // s
  int n0 = blockIdx.y * TS;   // f
  const float* Bp = gout + (size_t)b * N_ * F_;
  int kbeg = ks * KCH;
  __shared__ float As[KT][TS + 4];
  __shared__ float Bs[KT][TS + 4];
  int tid = threadIdx.x;
  int tm = (tid & 15) * 4, tn = (tid >> 4) * 4;
  int arow = tid >> 2, acol = (tid & 3) * 4;
  int brow = tid >> 4, bcol = (tid & 15) * 4;
  float acc[4][4] = {};
  for (int k0 = kbeg; k0 < kbeg + KCH; k0 += KT) {
    float4 av = *(const float4*)(Wproj + (size_t)(m0 + arow) * N_ + (k0 + acol));
    float4 bv = *(const float4*)(Bp + (size_t)(k0 + brow) * F_ + (n0 + bcol));
    __syncthreads();
    As[acol + 0][arow] = av.x; As[acol + 1][arow] = av.y;
    As[acol + 2][arow] = av.z; As[acol + 3][arow] = av.w;
    *(float4*)&Bs[brow][bcol] = bv;
    __syncthreads();
    mm_inner(As, Bs, tm, tn, acc);
  }
#pragma unroll
  for (int i = 0; i < 4; ++i) {
    int row = m0 + tm + i;
#pragma unroll
    for (int j = 0; j < 4; ++j) {
      atomicAdd(&P[((size_t)b * S_ + row) * F_ + n0 + tn + j], acc[i][j]);
    }
  }
}

// ---------------- GEMM 4 ----------------
__global__ __launch_bounds__(128) void temp_kernel(
    const float* __restrict__ P, const float* __restrict__ bproj,
    const float* __restrict__ Wtemp, const float* __restrict__ btemp,
    float* __restrict__ out) {
  int bs = blockIdx.x;          // 0..B*S-1
  int s = bs & (S_ - 1);
  int g = threadIdx.x;
  __shared__ float prow[F_];
  float bp = bproj[s];
  for (int f = g; f < F_; f += 128) prow[f] = P[(size_t)bs * F_ + f] + bp;
  __syncthreads();
  float acc = btemp[g];
  const float* w = Wtemp + (size_t)g * F_;
  for (int f = 0; f < F_; f += 4) {
    float4 pv = *(const float4*)&prow[f];
    float4 wv = *(const float4*)&w[f];
    acc += pv.x * wv.x + pv.y * wv.y + pv.z * wv.z + pv.w * wv.w;
  }
  out[(size_t)bs * DG_ + g] = acc;
}

// ---------------- launcher ----------------
extern "C" void kernel_launch(void* const* d_in, const int* in_sizes, int n_in,
                              void* d_out, int out_size, void* d_ws, size_t ws_size,
                              hipStream_t stream) {
  const float* x_enc   = (const float*)d_in[0];
  const float* mask    = (const float*)d_in[1];
  const int*   ei      = (const int*)d_in[2];
  const float* Wq      = (const float*)d_in[3];
  const float* bq      = (const float*)d_in[4];
  const float* Wm      = (const float*)d_in[5];
  const float* bm      = (const float*)d_in[6];
  const float* Wlin    = (const float*)d_in[7];
  const float* att_src = (const float*)d_in[8];
  const float* att_dst = (const float*)d_in[9];
  const float* bias_gat= (const float*)d_in[10];
  const float* Wproj   = (const float*)d_in[11];
  const float* bproj   = (const float*)d_in[12];
  const float* Wtemp   = (const float*)d_in[13];
  const float* btemp   = (const float*)d_in[14];
  float* outp = (float*)d_out;

  char* ws = (char*)d_ws;
  size_t off = 0;
  auto alloc = [&](size_t bytes) {
    char* p = ws + off;
    off = (off + bytes + 255) & ~(size_t)255;
    return p;
  };

  // regionA: union of {Wq_bf16 (20,578,304) + xeT (786,432) + xbuf (30,769,152)}
  //          and gat fp32 (61,440,000). gat written only after the first three are dead.
  char* regionA = alloc((size_t)BN_ * F_ * 4);                 // 61,440,000
  __hip_bfloat16* Wq_b = (__hip_bfloat16*)regionA;
  __hip_bfloat16* xeT  = (__hip_bfloat16*)(regionA + (size_t)MPADQ * S_ * 2);
  __hip_bfloat16* xb   = (__hip_bfloat16*)(regionA + (size_t)MPADQ * S_ * 2
                                                   + (size_t)B_ * D_ * S_ * 2);
  float* gat = (float*)regionA;

  __hip_bfloat16* xp    = (__hip_bfloat16*)alloc((size_t)BN_ * F_ * 2);
  __hip_bfloat16* WlinB = (__hip_bfloat16*)alloc((size_t)F_ * D_ * 2);
  float* a_src = (float*)alloc((size_t)BN_ * H_ * 4);
  float* a_dst = (float*)alloc((size_t)BN_ * H_ * 4);
  int* counts  = (int*)alloc((size_t)BN_ * 4);
  int* offsb   = (int*)alloc((size_t)BN_ * 4);
  int* cursor  = (int*)alloc((size_t)BN_ * 4);
  int* col     = (int*)alloc((size_t)ETOT_ * 4);
  float* P     = (float*)alloc((size_t)B_ * S_ * F_ * 4);
  if (off > ws_size) return;  // workspace too small: fail loudly via absmax

  hipMemsetAsync(counts, 0, (size_t)BN_ * 4, stream);
  hipMemsetAsync(P, 0, (size_t)B_ * S_ * F_ * 4, stream);
  // zero the pad rows of xb (rows BN_..MPADL-1) read by gemm_lin A-loads
  hipMemsetAsync(xb + (size_t)BN_ * F_, 0, (size_t)(MPADL - BN_) * F_ * 2, stream);

  // conversions
  conv_wq_kernel<<<(MPADQ * S_ / 4 + 255) / 256, 256, 0, stream>>>(Wq, Wq_b);
  conv_xeT_kernel<<<(B_ * S_ * D_ + 255) / 256, 256, 0, stream>>>(x_enc, xeT);
  conv_wlin_kernel<<<(F_ * D_ / 4 + 255) / 256, 256, 0, stream>>>(Wlin, WlinB);

  // gemm_q: x[b,n,d] = Wq·xe + bq + mask*Wm + bm   (bf16 MFMA)
  mfma_gemm_nt<1><<<dim3(MPADQ / 128, F_ / 128, B_), 256, 0, stream>>>(
      Wq_b, xeT, xb, S_, N_, (size_t)D_ * S_, (size_t)N_ * F_,
      bq, mask, Wm, bm);
  // gemm_lin: xp = x·Wlin^T   (bf16 MFMA)
  mfma_gemm_nt<0><<<dim3(MPADL / 128, F_ / 128, 1), 256, 0, stream>>>(
      xb, WlinB, xp, D_, BN_, 0, 0, nullptr, nullptr, nullptr, nullptr);

  att_kernel<<<(BN_ * H_ + 3) / 4, 256, 0, stream>>>(xp, att_src, att_dst, a_src, a_dst);
  count_kernel<<<(2 * E_ + 255) / 256, 256, 0, stream>>>(ei, counts);
  scan_kernel<<<1, 1024, 0, stream>>>(counts, offsb, cursor);
  fill_kernel<<<(ETOT_ + 255) / 256, 256, 0, stream>>>(ei, cursor, col);
  agg_kernel<<<BN_, 384, 0, stream>>>(offsb, cursor, col, a_src, a_dst, xp, bias_gat, gat);
  gemm_proj_kernel<<<dim3(S_ / TS, F_ / TS, B_ * KSPLIT), 256, 0, stream>>>(Wproj, gat, P);
  temp_kernel<<<B_ * S_, 128, 0, stream>>>(P, bproj, Wtemp, btemp, outp);
}

// Round 3
// 663.593 us; speedup vs baseline: 2.0138x; 1.2633x over previous
//
#include <hip/hip_runtime.h>
#include <hip/hip_bf16.h>
#include <cstdint>

// Problem constants
#define B_   2
#define S_   512
#define N_   20000
#define H_   3
#define C_   128
#define E_   320000
#define DG_  128
#define D_   384
#define BN_  (B_ * N_)            // 40000
#define F_   (H_ * C_)            // 384
#define ETOT_ (B_ * E_ + BN_)     // 680000

#define MPADQ 20096               // N_ padded to 128
#define MPADL 40064               // BN_ padded to 128

// split-K for proj GEMM (K = N_ = 20000 = 625 * 32)
#define PNS 20
#define PCHUNK 1024               // 32 k-iters per split (last split: 544)

using short8  = __attribute__((ext_vector_type(8))) short;
using floatx4 = __attribute__((ext_vector_type(4))) float;

// ================= conversion kernels =================
struct bf4 { __hip_bfloat16 a, b, c, d; };

__global__ __launch_bounds__(256) void conv_wq_kernel(const float* __restrict__ Wq,
                                                      __hip_bfloat16* __restrict__ o) {
  int idx = blockIdx.x * 256 + threadIdx.x;   // over MPADQ*512/4
  if (idx >= (MPADQ * 512) / 4) return;
  int e = idx * 4;
  int row = e >> 9;
  float4 v = make_float4(0.f, 0.f, 0.f, 0.f);
  if (row < N_) v = *(const float4*)(Wq + e);
  bf4 r{__float2bfloat16(v.x), __float2bfloat16(v.y),
        __float2bfloat16(v.z), __float2bfloat16(v.w)};
  *(bf4*)(o + e) = r;
}

// xe [B][S][D] fp32 -> xeT [B][D][S] bf16
__global__ __launch_bounds__(256) void conv_xeT_kernel(const float* __restrict__ xe,
                                                       __hip_bfloat16* __restrict__ o) {
  int idx = blockIdx.x * 256 + threadIdx.x;
  if (idx >= B_ * S_ * D_) return;
  int s = idx & 511;
  int rest = idx >> 9;
  int d = rest % D_;
  int b = rest / D_;
  o[idx] = __float2bfloat16(xe[(size_t)b * S_ * D_ + (size_t)s * D_ + d]);
}

// generic fp32 -> bf16 (length multiple of 4)
__global__ __launch_bounds__(256) void conv_bf16_kernel(const float* __restrict__ W,
                                                        __hip_bfloat16* __restrict__ o,
                                                        int n4) {
  int idx = blockIdx.x * 256 + threadIdx.x;
  if (idx >= n4) return;
  int e = idx * 4;
  float4 v = *(const float4*)(W + e);
  bf4 r{__float2bfloat16(v.x), __float2bfloat16(v.y),
        __float2bfloat16(v.z), __float2bfloat16(v.w)};
  *(bf4*)(o + e) = r;
}

// ================= bf16 MFMA GEMM (NT: A[m][k], Bt[n][k], both k-major) =================
// block tile 128x128, BK=32, 256 threads = 4 waves, wave tile 64x64 (4x4 of 16x16x32)
template <int EPI>
__global__ __launch_bounds__(256) void mfma_gemm_nt(
    const __hip_bfloat16* __restrict__ A, const __hip_bfloat16* __restrict__ Bt,
    __hip_bfloat16* __restrict__ Cout, int K, int Mvalid,
    size_t bstrideB, size_t bstrideC,
    const float* __restrict__ bq, const float* __restrict__ mask,
    const float* __restrict__ Wm, const float* __restrict__ bm) {
  const int tid = threadIdx.x;
  const int m0 = blockIdx.x * 128;
  const int n0 = blockIdx.y * 128;
  const int bz = blockIdx.z;

  const unsigned short* Ap = (const unsigned short*)A;
  const unsigned short* Bp = (const unsigned short*)(Bt + bstrideB * bz);

  __shared__ __align__(16) unsigned short As[128][40];
  __shared__ __align__(16) unsigned short Bs[128][40];

  const int wave = tid >> 6, lane = tid & 63;
  const int wm = (wave & 1) * 64, wn = (wave >> 1) * 64;
  const int lrow = lane & 15, lk = (lane >> 4) * 8;

  const int srow = tid >> 2;            // 0..63
  const int skoff = (tid & 3) * 8;      // 0,8,16,24

  floatx4 acc[4][4];
#pragma unroll
  for (int i = 0; i < 4; ++i)
#pragma unroll
    for (int j = 0; j < 4; ++j) acc[i][j] = floatx4{0.f, 0.f, 0.f, 0.f};

  for (int k0 = 0; k0 < K; k0 += 32) {
    int4 av0 = *(const int4*)(Ap + (size_t)(m0 + srow) * K + k0 + skoff);
    int4 av1 = *(const int4*)(Ap + (size_t)(m0 + 64 + srow) * K + k0 + skoff);
    int4 bv0 = *(const int4*)(Bp + (size_t)(n0 + srow) * K + k0 + skoff);
    int4 bv1 = *(const int4*)(Bp + (size_t)(n0 + 64 + srow) * K + k0 + skoff);
    __syncthreads();
    *(int4*)&As[srow][skoff] = av0;
    *(int4*)&As[64 + srow][skoff] = av1;
    *(int4*)&Bs[srow][skoff] = bv0;
    *(int4*)&Bs[64 + srow][skoff] = bv1;
    __syncthreads();
    short8 af[4], bf[4];
#pragma unroll
    for (int mt = 0; mt < 4; ++mt)
      af[mt] = *(const short8*)&As[wm + mt * 16 + lrow][lk];
#pragma unroll
    for (int nt = 0; nt < 4; ++nt)
      bf[nt] = *(const short8*)&Bs[wn + nt * 16 + lrow][lk];
#pragma unroll
    for (int mt = 0; mt < 4; ++mt)
#pragma unroll
      for (int nt = 0; nt < 4; ++nt)
        acc[mt][nt] = __builtin_amdgcn_mfma_f32_16x16x32_bf16(af[mt], bf[nt],
                                                              acc[mt][nt], 0, 0, 0);
  }

  // epilogue: C/D layout col=lane&15, row=(lane>>4)*4+r
  __hip_bfloat16* Cb = Cout + bstrideC * bz;
#pragma unroll
  for (int mt = 0; mt < 4; ++mt) {
#pragma unroll
    for (int r = 0; r < 4; ++r) {
      int rg = m0 + wm + mt * 16 + (lane >> 4) * 4 + r;
      if (rg < Mvalid) {
        float bqv = 0.f, mkv = 0.f;
        if (EPI) {
          bqv = bq[rg];
          mkv = mask[bz * N_ + rg];
        }
#pragma unroll
        for (int nt = 0; nt < 4; ++nt) {
          int cg = n0 + wn + nt * 16 + lrow;
          float v = acc[mt][nt][r];
          if (EPI) v += bqv + mkv * Wm[cg] + bm[cg];
          Cb[(size_t)rg * F_ + cg] = __float2bfloat16(v);
        }
      }
    }
  }
}

// ================= proj GEMM: split-K bf16 MFMA, fp32 partial output =================
// P_part[bz][s][f], bz = b*PNS+ks ; A = WprojB [S][N_] bf16, Bt = gatT [b][F][N_] bf16
__global__ __launch_bounds__(256) void gemm_proj_mfma(
    const __hip_bfloat16* __restrict__ A, const __hip_bfloat16* __restrict__ Bt,
    float* __restrict__ Ppart) {
  const int tid = threadIdx.x;
  const int m0 = blockIdx.x * 128;       // s
  const int n0 = blockIdx.y * 128;       // f
  const int bz = blockIdx.z;             // b*PNS + ks
  const int b = bz / PNS, ks = bz - b * PNS;
  const int kbeg = ks * PCHUNK;
  const int kend = (kbeg + PCHUNK < N_) ? (kbeg + PCHUNK) : N_;

  const unsigned short* Ap = (const unsigned short*)A;
  const unsigned short* Bp = (const unsigned short*)(Bt + (size_t)b * F_ * N_);

  __shared__ __align__(16) unsigned short As[128][40];
  __shared__ __align__(16) unsigned short Bs[128][40];

  const int wave = tid >> 6, lane = tid & 63;
  const int wm = (wave & 1) * 64, wn = (wave >> 1) * 64;
  const int lrow = lane & 15, lk = (lane >> 4) * 8;
  const int srow = tid >> 2;
  const int skoff = (tid & 3) * 8;

  floatx4 acc[4][4];
#pragma unroll
  for (int i = 0; i < 4; ++i)
#pragma unroll
    for (int j = 0; j < 4; ++j) acc[i][j] = floatx4{0.f, 0.f, 0.f, 0.f};

  for (int k0 = kbeg; k0 < kend; k0 += 32) {
    int4 av0 = *(const int4*)(Ap + (size_t)(m0 + srow) * N_ + k0 + skoff);
    int4 av1 = *(const int4*)(Ap + (size_t)(m0 + 64 + srow) * N_ + k0 + skoff);
    int4 bv0 = *(const int4*)(Bp + (size_t)(n0 + srow) * N_ + k0 + skoff);
    int4 bv1 = *(const int4*)(Bp + (size_t)(n0 + 64 + srow) * N_ + k0 + skoff);
    __syncthreads();
    *(int4*)&As[srow][skoff] = av0;
    *(int4*)&As[64 + srow][skoff] = av1;
    *(int4*)&Bs[srow][skoff] = bv0;
    *(int4*)&Bs[64 + srow][skoff] = bv1;
    __syncthreads();
    short8 af[4], bf[4];
#pragma unroll
    for (int mt = 0; mt < 4; ++mt)
      af[mt] = *(const short8*)&As[wm + mt * 16 + lrow][lk];
#pragma unroll
    for (int nt = 0; nt < 4; ++nt)
      bf[nt] = *(const short8*)&Bs[wn + nt * 16 + lrow][lk];
#pragma unroll
    for (int mt = 0; mt < 4; ++mt)
#pragma unroll
      for (int nt = 0; nt < 4; ++nt)
        acc[mt][nt] = __builtin_amdgcn_mfma_f32_16x16x32_bf16(af[mt], bf[nt],
                                                              acc[mt][nt], 0, 0, 0);
  }

  float* Pp = Ppart + (size_t)bz * S_ * F_;
#pragma unroll
  for (int mt = 0; mt < 4; ++mt) {
#pragma unroll
    for (int r = 0; r < 4; ++r) {
      int rg = m0 + wm + mt * 16 + (lane >> 4) * 4 + r;
#pragma unroll
      for (int nt = 0; nt < 4; ++nt) {
        int cg = n0 + wn + nt * 16 + lrow;
        Pp[(size_t)rg * F_ + cg] = acc[mt][nt][r];
      }
    }
  }
}

// ================= transpose gat [b][N][F] bf16 -> gatT [b][F][N] bf16 =================
#define TT 64
__global__ __launch_bounds__(256) void transpose_kernel(
    const __hip_bfloat16* __restrict__ in, __hip_bfloat16* __restrict__ out) {
  __shared__ unsigned short tile[TT][TT + 8];
  int n0 = blockIdx.x * TT, f0 = blockIdx.y * TT, b = blockIdx.z;
  int t = threadIdx.x;
  const unsigned short* ip = (const unsigned short*)(in + (size_t)b * N_ * F_);
  unsigned short* op = (unsigned short*)(out + (size_t)b * F_ * N_);
  int fo = (t & 7) * 8, ro = t >> 3;  // ro 0..31
#pragma unroll
  for (int half = 0; half < 2; ++half) {
    int r = ro + half * 32;
    if (n0 + r < N_)
      *(int4*)&tile[r][fo] = *(const int4*)(ip + (size_t)(n0 + r) * F_ + f0 + fo);
    else
      *(int4*)&tile[r][fo] = make_int4(0, 0, 0, 0);
  }
  __syncthreads();
  int no = (t & 7) * 8, fo2 = t >> 3;
  if (n0 + no + 8 <= N_) {
#pragma unroll
    for (int half = 0; half < 2; ++half) {
      int f = fo2 + half * 32;
      unsigned short v[8];
#pragma unroll
      for (int j = 0; j < 8; ++j) v[j] = tile[no + j][f];
      *(int4*)(op + (size_t)(f0 + f) * N_ + n0 + no) = *(int4*)v;
    }
  }
}

// ---------------- attention coefficients ----------------
__global__ __launch_bounds__(256) void att_kernel(
    const __hip_bfloat16* __restrict__ xp, const float* __restrict__ att_src,
    const float* __restrict__ att_dst, float* __restrict__ a_src,
    float* __restrict__ a_dst) {
  int gid = blockIdx.x * blockDim.x + threadIdx.x;
  int wid = gid >> 6;
  int lane = threadIdx.x & 63;
  if (wid >= BN_ * H_) return;
  int i = wid / H_, h = wid - i * H_;
  const __hip_bfloat16* row = xp + (size_t)i * F_ + h * C_;
  const float* as = att_src + h * C_;
  const float* ad = att_dst + h * C_;
  float v0 = __bfloat162float(row[lane]), v1 = __bfloat162float(row[lane + 64]);
  float s1 = v0 * as[lane] + v1 * as[lane + 64];
  float s2 = v0 * ad[lane] + v1 * ad[lane + 64];
#pragma unroll
  for (int off = 32; off > 0; off >>= 1) {
    s1 += __shfl_down(s1, off);
    s2 += __shfl_down(s2, off);
  }
  if (lane == 0) {
    a_src[i * H_ + h] = s1;
    a_dst[i * H_ + h] = s2;
  }
}

// ---------------- CSR build ----------------
__global__ __launch_bounds__(256) void count_kernel(const int* __restrict__ ei,
                                                    int* __restrict__ counts) {
  int idx = blockIdx.x * blockDim.x + threadIdx.x;
  if (idx >= 2 * E_) return;
  int b = (idx >= E_) ? 1 : 0;
  int e = idx - b * E_;
  int d = ei[E_ + e];
  atomicAdd(&counts[b * N_ + d], 1);
}

__global__ __launch_bounds__(1024) void scan_kernel(const int* __restrict__ counts,
                                                    int* __restrict__ offs,
                                                    int* __restrict__ cursor) {
  __shared__ int sdata[1024];
  __shared__ int running_s;
  int t = threadIdx.x;
  if (t == 0) running_s = 0;
  __syncthreads();
  for (int base = 0; base < BN_; base += 1024) {
    int i = base + t;
    int v = (i < BN_) ? (counts[i] + 1) : 0;  // +1 = self loop
    int runbase = running_s;
    __syncthreads();
    sdata[t] = v;
    __syncthreads();
    int val = v;
    for (int o = 1; o < 1024; o <<= 1) {
      int add = (t >= o) ? sdata[t - o] : 0;
      __syncthreads();
      val += add;
      sdata[t] = val;
      __syncthreads();
    }
    int excl = val - v;
    if (i < BN_) { offs[i] = runbase + excl; cursor[i] = runbase + excl; }
    int total = sdata[1023];
    __syncthreads();
    if (t == 0) running_s = runbase + total;
    __syncthreads();
  }
}

__global__ __launch_bounds__(256) void fill_kernel(const int* __restrict__ ei,
                                                   int* __restrict__ cursor,
                                                   int* __restrict__ col) {
  int idx = blockIdx.x * blockDim.x + threadIdx.x;
  if (idx >= ETOT_) return;
  if (idx < 2 * E_) {
    int b = (idx >= E_) ? 1 : 0;
    int e = idx - b * E_;
    int s = ei[e];
    int d = ei[E_ + e];
    int pos = atomicAdd(&cursor[b * N_ + d], 1);
    col[pos] = b * N_ + s;
  } else {
    int i = idx - 2 * E_;
    int pos = atomicAdd(&cursor[i], 1);
    col[pos] = i;
  }
}

// ---------------- segment softmax + aggregation (bf16 out) ----------------
#define CHK 128
__global__ __launch_bounds__(384) void agg_kernel(
    const int* __restrict__ offs, const int* __restrict__ ends,
    const int* __restrict__ col, const float* __restrict__ a_src,
    const float* __restrict__ a_dst, const __hip_bfloat16* __restrict__ xp,
    const float* __restrict__ bias_gat, __hip_bfloat16* __restrict__ out) {
  int i = blockIdx.x;
  int t = threadIdx.x;
  int h = t >> 7;        // head (C=128)
  int c = t & 127;
  int beg = offs[i];
  int nE = ends[i] - beg;
  __shared__ float red[384];
  __shared__ float sm[H_], sr[H_], sad[H_];
  __shared__ int scol[CHK];
  __shared__ float salpha[CHK][H_];
  if (t < H_) sad[t] = a_dst[i * H_ + t];
  float adh = a_dst[i * H_ + h];

  // phase A: per-head max
  float m = -1e30f;
  for (int j = c; j < nE; j += 128) {
    int s = col[beg + j];
    float e = a_src[s * H_ + h] + adh;
    e = (e > 0.f) ? e : 0.2f * e;
    m = fmaxf(m, e);
  }
  red[t] = m;
  __syncthreads();
#pragma unroll
  for (int o = 64; o > 0; o >>= 1) {
    if (c < o) red[t] = fmaxf(red[t], red[t + o]);
    __syncthreads();
  }
  float mh = red[h * 128];
  if (c == 0) sm[h] = mh;
  __syncthreads();

  // phase B: per-head denom
  float ssum = 0.f;
  for (int j = c; j < nE; j += 128) {
    int s = col[beg + j];
    float e = a_src[s * H_ + h] + adh;
    e = (e > 0.f) ? e : 0.2f * e;
    ssum += __expf(e - mh);
  }
  red[t] = ssum;
  __syncthreads();
#pragma unroll
  for (int o = 64; o > 0; o >>= 1) {
    if (c < o) red[t] += red[t + o];
    __syncthreads();
  }
  if (c == 0) sr[h] = 1.0f / red[h * 128];

  // phase C: chunked — stage col + alpha in LDS, then gather bf16 xp
  float acc = 0.f;
  for (int c0 = 0; c0 < nE; c0 += CHK) {
    int cn = min(CHK, nE - c0);
    __syncthreads();
    if (t < cn) {
      int s = col[beg + c0 + t];
      scol[t] = s;
#pragma unroll
      for (int hh = 0; hh < H_; ++hh) {
        float e = a_src[s * H_ + hh] + sad[hh];
        e = (e > 0.f) ? e : 0.2f * e;
        salpha[t][hh] = __expf(e - sm[hh]) * sr[hh];
      }
    }
    __syncthreads();
#pragma unroll 4
    for (int j = 0; j < cn; ++j) {
      int s = scol[j];
      acc = fmaf(salpha[j][h], __bfloat162float(xp[(size_t)s * F_ + t]), acc);
    }
  }
  out[(size_t)i * F_ + t] = __float2bfloat16(acc + bias_gat[t]);
}

// ---------------- GEMM 4: reduce split-K partials + temp projection ----------------
__global__ __launch_bounds__(128) void temp_kernel(
    const float* __restrict__ Ppart, const float* __restrict__ bproj,
    const float* __restrict__ Wtemp, const float* __restrict__ btemp,
    float* __restrict__ out) {
  int bs = blockIdx.x;          // 0..B*S-1
  int b = bs >> 9;
  int s = bs & (S_ - 1);
  int g = threadIdx.x;
  __shared__ float prow[F_];
  float bp = bproj[s];
  for (int f = g; f < F_; f += 128) {
    float acc = bp;
    const float* pp = Ppart + ((size_t)b * PNS * S_ + s) * F_ + f;
    for (int ns = 0; ns < PNS; ++ns) acc += pp[(size_t)ns * S_ * F_];
    prow[f] = acc;
  }
  __syncthreads();
  float acc = btemp[g];
  const float* w = Wtemp + (size_t)g * F_;
  for (int f = 0; f < F_; f += 4) {
    float4 pv = *(const float4*)&prow[f];
    float4 wv = *(const float4*)&w[f];
    acc += pv.x * wv.x + pv.y * wv.y + pv.z * wv.z + pv.w * wv.w;
  }
  out[(size_t)bs * DG_ + g] = acc;
}

// ---------------- launcher ----------------
extern "C" void kernel_launch(void* const* d_in, const int* in_sizes, int n_in,
                              void* d_out, int out_size, void* d_ws, size_t ws_size,
                              hipStream_t stream) {
  const float* x_enc   = (const float*)d_in[0];
  const float* mask    = (const float*)d_in[1];
  const int*   ei      = (const int*)d_in[2];
  const float* Wq      = (const float*)d_in[3];
  const float* bq      = (const float*)d_in[4];
  const float* Wm      = (const float*)d_in[5];
  const float* bm      = (const float*)d_in[6];
  const float* Wlin    = (const float*)d_in[7];
  const float* att_src = (const float*)d_in[8];
  const float* att_dst = (const float*)d_in[9];
  const float* bias_gat= (const float*)d_in[10];
  const float* Wproj   = (const float*)d_in[11];
  const float* bproj   = (const float*)d_in[12];
  const float* Wtemp   = (const float*)d_in[13];
  const float* btemp   = (const float*)d_in[14];
  float* outp = (float*)d_out;

  char* ws = (char*)d_ws;
  size_t off = 0;
  auto alloc = [&](size_t bytes) {
    char* p = ws + off;
    off = (off + bytes + 255) & ~(size_t)255;
    return p;
  };

  // regionA timeline:
  //   phase 1 (conv/gemm_q/gemm_lin): Wq_b (0..20.6M) + xeT + xb (21.4..52.1M)
  //   phase 2 (agg):                  gat bf16 at 0..30.7M
  //   phase 3 (transpose):            gatT at 31.46..62.2M (reads gat)
  //   phase 4 (gemm_proj):            Ppart fp32 at 0..31.46M (reads gatT)
  const size_t GATT_OFF = 31457536;  // > Ppart end (31,457,280), 256-aligned
  char* regionA = alloc(GATT_OFF + (size_t)B_ * F_ * N_ * 2);   // 62.2 MB
  __hip_bfloat16* Wq_b = (__hip_bfloat16*)regionA;
  __hip_bfloat16* xeT  = (__hip_bfloat16*)(regionA + (size_t)MPADQ * S_ * 2);
  __hip_bfloat16* xb   = (__hip_bfloat16*)(regionA + (size_t)MPADQ * S_ * 2
                                                   + (size_t)B_ * D_ * S_ * 2);
  __hip_bfloat16* gat  = (__hip_bfloat16*)regionA;
  __hip_bfloat16* gatT = (__hip_bfloat16*)(regionA + GATT_OFF);
  float* Ppart = (float*)regionA;

  __hip_bfloat16* xp     = (__hip_bfloat16*)alloc((size_t)BN_ * F_ * 2);
  __hip_bfloat16* WlinB  = (__hip_bfloat16*)alloc((size_t)F_ * D_ * 2);
  __hip_bfloat16* WprojB = (__hip_bfloat16*)alloc((size_t)S_ * N_ * 2);
  float* a_src = (float*)alloc((size_t)BN_ * H_ * 4);
  float* a_dst = (float*)alloc((size_t)BN_ * H_ * 4);
  int* counts  = (int*)alloc((size_t)BN_ * 4);
  int* offsb   = (int*)alloc((size_t)BN_ * 4);
  int* cursor  = (int*)alloc((size_t)BN_ * 4);
  int* col     = (int*)alloc((size_t)ETOT_ * 4);
  if (off > ws_size) return;  // workspace too small: fail loudly via absmax

  hipMemsetAsync(counts, 0, (size_t)BN_ * 4, stream);
  // zero the pad rows of xb (rows BN_..MPADL-1) read by gemm_lin A-loads
  hipMemsetAsync(xb + (size_t)BN_ * F_, 0, (size_t)(MPADL - BN_) * F_ * 2, stream);

  // conversions
  conv_wq_kernel<<<(MPADQ * S_ / 4 + 255) / 256, 256, 0, stream>>>(Wq, Wq_b);
  conv_xeT_kernel<<<(B_ * S_ * D_ + 255) / 256, 256, 0, stream>>>(x_enc, xeT);
  conv_bf16_kernel<<<(F_ * D_ / 4 + 255) / 256, 256, 0, stream>>>(Wlin, WlinB, F_ * D_ / 4);
  conv_bf16_kernel<<<(S_ * N_ / 4 + 255) / 256, 256, 0, stream>>>(Wproj, WprojB, S_ * N_ / 4);

  // gemm_q: x[b,n,d] = Wq·xe + bq + mask*Wm + bm   (bf16 MFMA)
  mfma_gemm_nt<1><<<dim3(MPADQ / 128, F_ / 128, B_), 256, 0, stream>>>(
      Wq_b, xeT, xb, S_, N_, (size_t)D_ * S_, (size_t)N_ * F_,
      bq, mask, Wm, bm);
  // gemm_lin: xp = x·Wlin^T   (bf16 MFMA)
  mfma_gemm_nt<0><<<dim3(MPADL / 128, F_ / 128, 1), 256, 0, stream>>>(
      xb, WlinB, xp, D_, BN_, 0, 0, nullptr, nullptr, nullptr, nullptr);

  att_kernel<<<(BN_ * H_ + 3) / 4, 256, 0, stream>>>(xp, att_src, att_dst, a_src, a_dst);
  count_kernel<<<(2 * E_ + 255) / 256, 256, 0, stream>>>(ei, counts);
  scan_kernel<<<1, 1024, 0, stream>>>(counts, offsb, cursor);
  fill_kernel<<<(ETOT_ + 255) / 256, 256, 0, stream>>>(ei, cursor, col);
  agg_kernel<<<BN_, 384, 0, stream>>>(offsb, cursor, col, a_src, a_dst, xp, bias_gat, gat);
  transpose_kernel<<<dim3((N_ + TT - 1) / TT, F_ / TT, B_), 256, 0, stream>>>(gat, gatT);
  gemm_proj_mfma<<<dim3(S_ / 128, F_ / 128, B_ * PNS), 256, 0, stream>>>(WprojB, gatT, Ppart);
  temp_kernel<<<B_ * S_, 128, 0, stream>>>(Ppart, bproj, Wtemp, btemp, outp);
}

// Round 4
// 643.736 us; speedup vs baseline: 2.0759x; 1.0308x over previous
//
#include <hip/hip_runtime.h>
#include <hip/hip_bf16.h>
#include <cstdint>

// Problem constants
#define B_   2
#define S_   512
#define N_   20000
#define H_   3
#define C_   128
#define E_   320000
#define DG_  128
#define D_   384
#define BN_  (B_ * N_)            // 40000
#define F_   (H_ * C_)            // 384
#define ETOT_ (B_ * E_ + BN_)     // 680000

#define MPADQ 20096               // N_ padded to 128
#define MPADL 40064               // BN_ padded to 128

// split-K for proj GEMM (K = N_ = 20000 = 625 * 32)
#define PNS 20
#define PCHUNK 1024               // 32 k-iters per split (last split: 544)

using short8  = __attribute__((ext_vector_type(8))) short;
using floatx4 = __attribute__((ext_vector_type(4))) float;

// ================= conversion kernels =================
struct bf4 { __hip_bfloat16 a, b, c, d; };

__global__ __launch_bounds__(256) void conv_wq_kernel(const float* __restrict__ Wq,
                                                      __hip_bfloat16* __restrict__ o) {
  int idx = blockIdx.x * 256 + threadIdx.x;   // over MPADQ*512/4
  if (idx >= (MPADQ * 512) / 4) return;
  int e = idx * 4;
  int row = e >> 9;
  float4 v = make_float4(0.f, 0.f, 0.f, 0.f);
  if (row < N_) v = *(const float4*)(Wq + e);
  bf4 r{__float2bfloat16(v.x), __float2bfloat16(v.y),
        __float2bfloat16(v.z), __float2bfloat16(v.w)};
  *(bf4*)(o + e) = r;
}

// xe [B][S][D] fp32 -> xeT [B][D][S] bf16
__global__ __launch_bounds__(256) void conv_xeT_kernel(const float* __restrict__ xe,
                                                       __hip_bfloat16* __restrict__ o) {
  int idx = blockIdx.x * 256 + threadIdx.x;
  if (idx >= B_ * S_ * D_) return;
  int s = idx & 511;
  int rest = idx >> 9;
  int d = rest % D_;
  int b = rest / D_;
  o[idx] = __float2bfloat16(xe[(size_t)b * S_ * D_ + (size_t)s * D_ + d]);
}

// generic fp32 -> bf16 (length multiple of 4)
__global__ __launch_bounds__(256) void conv_bf16_kernel(const float* __restrict__ W,
                                                        __hip_bfloat16* __restrict__ o,
                                                        int n4) {
  int idx = blockIdx.x * 256 + threadIdx.x;
  if (idx >= n4) return;
  int e = idx * 4;
  float4 v = *(const float4*)(W + e);
  bf4 r{__float2bfloat16(v.x), __float2bfloat16(v.y),
        __float2bfloat16(v.z), __float2bfloat16(v.w)};
  *(bf4*)(o + e) = r;
}

// ================= bf16 MFMA GEMM (NT: A[m][k], Bt[n][k], both k-major) =================
template <int EPI>
__global__ __launch_bounds__(256) void mfma_gemm_nt(
    const __hip_bfloat16* __restrict__ A, const __hip_bfloat16* __restrict__ Bt,
    __hip_bfloat16* __restrict__ Cout, int K, int Mvalid,
    size_t bstrideB, size_t bstrideC,
    const float* __restrict__ bq, const float* __restrict__ mask,
    const float* __restrict__ Wm, const float* __restrict__ bm) {
  const int tid = threadIdx.x;
  const int m0 = blockIdx.x * 128;
  const int n0 = blockIdx.y * 128;
  const int bz = blockIdx.z;

  const unsigned short* Ap = (const unsigned short*)A;
  const unsigned short* Bp = (const unsigned short*)(Bt + bstrideB * bz);

  __shared__ __align__(16) unsigned short As[128][40];
  __shared__ __align__(16) unsigned short Bs[128][40];

  const int wave = tid >> 6, lane = tid & 63;
  const int wm = (wave & 1) * 64, wn = (wave >> 1) * 64;
  const int lrow = lane & 15, lk = (lane >> 4) * 8;

  const int srow = tid >> 2;            // 0..63
  const int skoff = (tid & 3) * 8;      // 0,8,16,24

  floatx4 acc[4][4];
#pragma unroll
  for (int i = 0; i < 4; ++i)
#pragma unroll
    for (int j = 0; j < 4; ++j) acc[i][j] = floatx4{0.f, 0.f, 0.f, 0.f};

  for (int k0 = 0; k0 < K; k0 += 32) {
    int4 av0 = *(const int4*)(Ap + (size_t)(m0 + srow) * K + k0 + skoff);
    int4 av1 = *(const int4*)(Ap + (size_t)(m0 + 64 + srow) * K + k0 + skoff);
    int4 bv0 = *(const int4*)(Bp + (size_t)(n0 + srow) * K + k0 + skoff);
    int4 bv1 = *(const int4*)(Bp + (size_t)(n0 + 64 + srow) * K + k0 + skoff);
    __syncthreads();
    *(int4*)&As[srow][skoff] = av0;
    *(int4*)&As[64 + srow][skoff] = av1;
    *(int4*)&Bs[srow][skoff] = bv0;
    *(int4*)&Bs[64 + srow][skoff] = bv1;
    __syncthreads();
    short8 af[4], bf[4];
#pragma unroll
    for (int mt = 0; mt < 4; ++mt)
      af[mt] = *(const short8*)&As[wm + mt * 16 + lrow][lk];
#pragma unroll
    for (int nt = 0; nt < 4; ++nt)
      bf[nt] = *(const short8*)&Bs[wn + nt * 16 + lrow][lk];
#pragma unroll
    for (int mt = 0; mt < 4; ++mt)
#pragma unroll
      for (int nt = 0; nt < 4; ++nt)
        acc[mt][nt] = __builtin_amdgcn_mfma_f32_16x16x32_bf16(af[mt], bf[nt],
                                                              acc[mt][nt], 0, 0, 0);
  }

  __hip_bfloat16* Cb = Cout + bstrideC * bz;
#pragma unroll
  for (int mt = 0; mt < 4; ++mt) {
#pragma unroll
    for (int r = 0; r < 4; ++r) {
      int rg = m0 + wm + mt * 16 + (lane >> 4) * 4 + r;
      if (rg < Mvalid) {
        float bqv = 0.f, mkv = 0.f;
        if (EPI) {
          bqv = bq[rg];
          mkv = mask[bz * N_ + rg];
        }
#pragma unroll
        for (int nt = 0; nt < 4; ++nt) {
          int cg = n0 + wn + nt * 16 + lrow;
          float v = acc[mt][nt][r];
          if (EPI) v += bqv + mkv * Wm[cg] + bm[cg];
          Cb[(size_t)rg * F_ + cg] = __float2bfloat16(v);
        }
      }
    }
  }
}

// ================= proj GEMM: split-K bf16 MFMA, fp32 partial output =================
__global__ __launch_bounds__(256) void gemm_proj_mfma(
    const __hip_bfloat16* __restrict__ A, const __hip_bfloat16* __restrict__ Bt,
    float* __restrict__ Ppart) {
  const int tid = threadIdx.x;
  const int m0 = blockIdx.x * 128;       // s
  const int n0 = blockIdx.y * 128;       // f
  const int bz = blockIdx.z;             // b*PNS + ks
  const int b = bz / PNS, ks = bz - b * PNS;
  const int kbeg = ks * PCHUNK;
  const int kend = (kbeg + PCHUNK < N_) ? (kbeg + PCHUNK) : N_;

  const unsigned short* Ap = (const unsigned short*)A;
  const unsigned short* Bp = (const unsigned short*)(Bt + (size_t)b * F_ * N_);

  __shared__ __align__(16) unsigned short As[128][40];
  __shared__ __align__(16) unsigned short Bs[128][40];

  const int wave = tid >> 6, lane = tid & 63;
  const int wm = (wave & 1) * 64, wn = (wave >> 1) * 64;
  const int lrow = lane & 15, lk = (lane >> 4) * 8;
  const int srow = tid >> 2;
  const int skoff = (tid & 3) * 8;

  floatx4 acc[4][4];
#pragma unroll
  for (int i = 0; i < 4; ++i)
#pragma unroll
    for (int j = 0; j < 4; ++j) acc[i][j] = floatx4{0.f, 0.f, 0.f, 0.f};

  for (int k0 = kbeg; k0 < kend; k0 += 32) {
    int4 av0 = *(const int4*)(Ap + (size_t)(m0 + srow) * N_ + k0 + skoff);
    int4 av1 = *(const int4*)(Ap + (size_t)(m0 + 64 + srow) * N_ + k0 + skoff);
    int4 bv0 = *(const int4*)(Bp + (size_t)(n0 + srow) * N_ + k0 + skoff);
    int4 bv1 = *(const int4*)(Bp + (size_t)(n0 + 64 + srow) * N_ + k0 + skoff);
    __syncthreads();
    *(int4*)&As[srow][skoff] = av0;
    *(int4*)&As[64 + srow][skoff] = av1;
    *(int4*)&Bs[srow][skoff] = bv0;
    *(int4*)&Bs[64 + srow][skoff] = bv1;
    __syncthreads();
    short8 af[4], bf[4];
#pragma unroll
    for (int mt = 0; mt < 4; ++mt)
      af[mt] = *(const short8*)&As[wm + mt * 16 + lrow][lk];
#pragma unroll
    for (int nt = 0; nt < 4; ++nt)
      bf[nt] = *(const short8*)&Bs[wn + nt * 16 + lrow][lk];
#pragma unroll
    for (int mt = 0; mt < 4; ++mt)
#pragma unroll
      for (int nt = 0; nt < 4; ++nt)
        acc[mt][nt] = __builtin_amdgcn_mfma_f32_16x16x32_bf16(af[mt], bf[nt],
                                                              acc[mt][nt], 0, 0, 0);
  }

  float* Pp = Ppart + (size_t)bz * S_ * F_;
#pragma unroll
  for (int mt = 0; mt < 4; ++mt) {
#pragma unroll
    for (int r = 0; r < 4; ++r) {
      int rg = m0 + wm + mt * 16 + (lane >> 4) * 4 + r;
#pragma unroll
      for (int nt = 0; nt < 4; ++nt) {
        int cg = n0 + wn + nt * 16 + lrow;
        Pp[(size_t)rg * F_ + cg] = acc[mt][nt][r];
      }
    }
  }
}

// ================= transpose gat [b][N][F] bf16 -> gatT [b][F][N] bf16 =================
#define TT 64
__global__ __launch_bounds__(256) void transpose_kernel(
    const __hip_bfloat16* __restrict__ in, __hip_bfloat16* __restrict__ out) {
  __shared__ unsigned short tile[TT][TT + 8];
  int n0 = blockIdx.x * TT, f0 = blockIdx.y * TT, b = blockIdx.z;
  int t = threadIdx.x;
  const unsigned short* ip = (const unsigned short*)(in + (size_t)b * N_ * F_);
  unsigned short* op = (unsigned short*)(out + (size_t)b * F_ * N_);
  int fo = (t & 7) * 8, ro = t >> 3;  // ro 0..31
#pragma unroll
  for (int half = 0; half < 2; ++half) {
    int r = ro + half * 32;
    if (n0 + r < N_)
      *(int4*)&tile[r][fo] = *(const int4*)(ip + (size_t)(n0 + r) * F_ + f0 + fo);
    else
      *(int4*)&tile[r][fo] = make_int4(0, 0, 0, 0);
  }
  __syncthreads();
  int no = (t & 7) * 8, fo2 = t >> 3;
  if (n0 + no + 8 <= N_) {
#pragma unroll
    for (int half = 0; half < 2; ++half) {
      int f = fo2 + half * 32;
      unsigned short v[8];
#pragma unroll
      for (int j = 0; j < 8; ++j) v[j] = tile[no + j][f];
      *(int4*)(op + (size_t)(f0 + f) * N_ + n0 + no) = *(int4*)v;
    }
  }
}

// ---------------- attention coefficients ----------------
__global__ __launch_bounds__(256) void att_kernel(
    const __hip_bfloat16* __restrict__ xp, const float* __restrict__ att_src,
    const float* __restrict__ att_dst, float* __restrict__ a_src,
    float* __restrict__ a_dst) {
  int gid = blockIdx.x * blockDim.x + threadIdx.x;
  int wid = gid >> 6;
  int lane = threadIdx.x & 63;
  if (wid >= BN_ * H_) return;
  int i = wid / H_, h = wid - i * H_;
  const __hip_bfloat16* row = xp + (size_t)i * F_ + h * C_;
  const float* as = att_src + h * C_;
  const float* ad = att_dst + h * C_;
  float v0 = __bfloat162float(row[lane]), v1 = __bfloat162float(row[lane + 64]);
  float s1 = v0 * as[lane] + v1 * as[lane + 64];
  float s2 = v0 * ad[lane] + v1 * ad[lane + 64];
#pragma unroll
  for (int off = 32; off > 0; off >>= 1) {
    s1 += __shfl_down(s1, off);
    s2 += __shfl_down(s2, off);
  }
  if (lane == 0) {
    a_src[i * H_ + h] = s1;
    a_dst[i * H_ + h] = s2;
  }
}

// ---------------- CSR build ----------------
__global__ __launch_bounds__(256) void count_kernel(const int* __restrict__ ei,
                                                    int* __restrict__ counts) {
  int idx = blockIdx.x * blockDim.x + threadIdx.x;
  if (idx >= 2 * E_) return;
  int b = (idx >= E_) ? 1 : 0;
  int e = idx - b * E_;
  int d = ei[E_ + e];
  atomicAdd(&counts[b * N_ + d], 1);
}

// single-block shuffle-based exclusive scan of (counts[i]+1)
__global__ __launch_bounds__(1024) void scan_kernel(const int* __restrict__ counts,
                                                    int* __restrict__ offs,
                                                    int* __restrict__ cursor) {
  __shared__ int wsum[16];
  __shared__ int carry;
  int t = threadIdx.x, wave = t >> 6, lane = t & 63;
  if (t == 0) carry = 0;
  __syncthreads();
  for (int base = 0; base < BN_; base += 1024) {
    int i = base + t;
    int v = (i < BN_) ? (counts[i] + 1) : 0;  // +1 = self loop
    int x = v;
#pragma unroll
    for (int o = 1; o < 64; o <<= 1) {
      int y = __shfl_up(x, o);
      if (lane >= o) x += y;
    }
    if (lane == 63) wsum[wave] = x;
    __syncthreads();
    int c = carry;
    if (wave == 0) {
      int w = (lane < 16) ? wsum[lane] : 0;
#pragma unroll
      for (int o = 1; o < 16; o <<= 1) {
        int y = __shfl_up(w, o);
        if (lane >= o) w += y;
      }
      if (lane < 16) wsum[lane] = w;
    }
    __syncthreads();
    int woff = (wave == 0) ? 0 : wsum[wave - 1];
    int excl = c + woff + x - v;
    if (i < BN_) { offs[i] = excl; cursor[i] = excl; }
    int total = wsum[15];
    __syncthreads();
    if (t == 0) carry = c + total;
  }
}

// fill CSR + per-edge softmax numerators (no max-subtraction: |e| << 80, fp32 exp safe)
// + per-node-head denominators via atomics
__global__ __launch_bounds__(256) void fill_kernel(
    const int* __restrict__ ei, const float* __restrict__ a_src,
    const float* __restrict__ a_dst, int* __restrict__ cursor,
    int* __restrict__ col, float4* __restrict__ ealpha,
    float* __restrict__ denom) {
  int idx = blockIdx.x * blockDim.x + threadIdx.x;
  if (idx >= ETOT_) return;
  int sg, dg;
  if (idx < 2 * E_) {
    int b = (idx >= E_) ? 1 : 0;
    int e = idx - b * E_;
    sg = b * N_ + ei[e];
    dg = b * N_ + ei[E_ + e];
  } else {
    sg = dg = idx - 2 * E_;
  }
  int pos = atomicAdd(&cursor[dg], 1);
  col[pos] = sg;
  float4 al;
  float ex[H_];
#pragma unroll
  for (int h = 0; h < H_; ++h) {
    float e = a_src[sg * H_ + h] + a_dst[dg * H_ + h];
    e = (e > 0.f) ? e : 0.2f * e;
    ex[h] = __expf(e);
    atomicAdd(&denom[dg * 4 + h], ex[h]);
  }
  al.x = ex[0]; al.y = ex[1]; al.z = ex[2]; al.w = 0.f;
  ealpha[pos] = al;
}

// ---------------- aggregation: single pass, precomputed alphas ----------------
#define CHK 64
__global__ __launch_bounds__(384) void agg_kernel(
    const int* __restrict__ offs, const int* __restrict__ ends,
    const int* __restrict__ col, const float4* __restrict__ ealpha,
    const float* __restrict__ denom, const __hip_bfloat16* __restrict__ xp,
    const float* __restrict__ bias_gat, __hip_bfloat16* __restrict__ out) {
  int i = blockIdx.x;
  int t = threadIdx.x;
  int h = t >> 7;        // head (C=128)
  int beg = offs[i];
  int nE = ends[i] - beg;
  __shared__ int scol[CHK];
  __shared__ float salpha[CHK][4];
  float rden = 1.0f / denom[i * 4 + h];

  float a0 = 0.f, a1 = 0.f;
  for (int c0 = 0; c0 < nE; c0 += CHK) {
    int cn = min(CHK, nE - c0);
    __syncthreads();
    if (t < cn) {
      scol[t] = col[beg + c0 + t];
    } else if (t >= CHK && t < CHK + cn) {
      *(float4*)&salpha[t - CHK][0] = ealpha[beg + c0 + t - CHK];
    }
    __syncthreads();
    int j = 0;
    for (; j + 8 <= cn; j += 8) {
      int s0 = scol[j + 0], s1 = scol[j + 1], s2 = scol[j + 2], s3 = scol[j + 3];
      int s4 = scol[j + 4], s5 = scol[j + 5], s6 = scol[j + 6], s7 = scol[j + 7];
      float x0 = __bfloat162float(xp[(size_t)s0 * F_ + t]);
      float x1 = __bfloat162float(xp[(size_t)s1 * F_ + t]);
      float x2 = __bfloat162float(xp[(size_t)s2 * F_ + t]);
      float x3 = __bfloat162float(xp[(size_t)s3 * F_ + t]);
      float x4 = __bfloat162float(xp[(size_t)s4 * F_ + t]);
      float x5 = __bfloat162float(xp[(size_t)s5 * F_ + t]);
      float x6 = __bfloat162float(xp[(size_t)s6 * F_ + t]);
      float x7 = __bfloat162float(xp[(size_t)s7 * F_ + t]);
      a0 = fmaf(salpha[j + 0][h], x0, a0);
      a1 = fmaf(salpha[j + 1][h], x1, a1);
      a0 = fmaf(salpha[j + 2][h], x2, a0);
      a1 = fmaf(salpha[j + 3][h], x3, a1);
      a0 = fmaf(salpha[j + 4][h], x4, a0);
      a1 = fmaf(salpha[j + 5][h], x5, a1);
      a0 = fmaf(salpha[j + 6][h], x6, a0);
      a1 = fmaf(salpha[j + 7][h], x7, a1);
    }
    for (; j < cn; ++j) {
      a0 = fmaf(salpha[j][h], __bfloat162float(xp[(size_t)scol[j] * F_ + t]), a0);
    }
  }
  out[(size_t)i * F_ + t] = __float2bfloat16((a0 + a1) * rden + bias_gat[t]);
}

// ---------------- GEMM 4: reduce split-K partials + temp projection ----------------
__global__ __launch_bounds__(128) void temp_kernel(
    const float* __restrict__ Ppart, const float* __restrict__ bproj,
    const float* __restrict__ Wtemp, const float* __restrict__ btemp,
    float* __restrict__ out) {
  int bs = blockIdx.x;          // 0..B*S-1
  int b = bs >> 9;
  int s = bs & (S_ - 1);
  int g = threadIdx.x;
  __shared__ float prow[F_];
  float bp = bproj[s];
  for (int f = g; f < F_; f += 128) {
    float acc = bp;
    const float* pp = Ppart + ((size_t)b * PNS * S_ + s) * F_ + f;
    for (int ns = 0; ns < PNS; ++ns) acc += pp[(size_t)ns * S_ * F_];
    prow[f] = acc;
  }
  __syncthreads();
  float acc = btemp[g];
  const float* w = Wtemp + (size_t)g * F_;
  for (int f = 0; f < F_; f += 4) {
    float4 pv = *(const float4*)&prow[f];
    float4 wv = *(const float4*)&w[f];
    acc += pv.x * wv.x + pv.y * wv.y + pv.z * wv.z + pv.w * wv.w;
  }
  out[(size_t)bs * DG_ + g] = acc;
}

// ---------------- launcher ----------------
extern "C" void kernel_launch(void* const* d_in, const int* in_sizes, int n_in,
                              void* d_out, int out_size, void* d_ws, size_t ws_size,
                              hipStream_t stream) {
  const float* x_enc   = (const float*)d_in[0];
  const float* mask    = (const float*)d_in[1];
  const int*   ei      = (const int*)d_in[2];
  const float* Wq      = (const float*)d_in[3];
  const float* bq      = (const float*)d_in[4];
  const float* Wm      = (const float*)d_in[5];
  const float* bm      = (const float*)d_in[6];
  const float* Wlin    = (const float*)d_in[7];
  const float* att_src = (const float*)d_in[8];
  const float* att_dst = (const float*)d_in[9];
  const float* bias_gat= (const float*)d_in[10];
  const float* Wproj   = (const float*)d_in[11];
  const float* bproj   = (const float*)d_in[12];
  const float* Wtemp   = (const float*)d_in[13];
  const float* btemp   = (const float*)d_in[14];
  float* outp = (float*)d_out;

  char* ws = (char*)d_ws;
  size_t off = 0;
  auto alloc = [&](size_t bytes) {
    char* p = ws + off;
    off = (off + bytes + 255) & ~(size_t)255;
    return p;
  };

  // regionA timeline:
  //   phase 1 (conv/gemm_q/gemm_lin): Wq_b + xeT + xb
  //   phase 2 (agg):                  gat bf16 at 0..30.7M
  //   phase 3 (transpose):            gatT at 31.46..62.2M (reads gat)
  //   phase 4 (gemm_proj):            Ppart fp32 at 0..31.46M (reads gatT)
  const size_t GATT_OFF = 31457536;  // > Ppart end (31,457,280), 256-aligned
  char* regionA = alloc(GATT_OFF + (size_t)B_ * F_ * N_ * 2);   // 62.2 MB
  __hip_bfloat16* Wq_b = (__hip_bfloat16*)regionA;
  __hip_bfloat16* xeT  = (__hip_bfloat16*)(regionA + (size_t)MPADQ * S_ * 2);
  __hip_bfloat16* xb   = (__hip_bfloat16*)(regionA + (size_t)MPADQ * S_ * 2
                                                   + (size_t)B_ * D_ * S_ * 2);
  __hip_bfloat16* gat  = (__hip_bfloat16*)regionA;
  __hip_bfloat16* gatT = (__hip_bfloat16*)(regionA + GATT_OFF);
  float* Ppart = (float*)regionA;

  __hip_bfloat16* xp     = (__hip_bfloat16*)alloc((size_t)BN_ * F_ * 2);
  __hip_bfloat16* WlinB  = (__hip_bfloat16*)alloc((size_t)F_ * D_ * 2);
  __hip_bfloat16* WprojB = (__hip_bfloat16*)alloc((size_t)S_ * N_ * 2);
  float* a_src = (float*)alloc((size_t)BN_ * H_ * 4);
  float* a_dst = (float*)alloc((size_t)BN_ * H_ * 4);
  int* counts  = (int*)alloc((size_t)BN_ * 4);
  int* offsb   = (int*)alloc((size_t)BN_ * 4);
  int* cursor  = (int*)alloc((size_t)BN_ * 4);
  int* col     = (int*)alloc((size_t)ETOT_ * 4);
  float4* ealpha = (float4*)alloc((size_t)ETOT_ * 16);
  float* denom = (float*)alloc((size_t)BN_ * 4 * 4);
  if (off > ws_size) return;  // workspace too small: fail loudly via absmax

  hipMemsetAsync(counts, 0, (size_t)BN_ * 4, stream);
  hipMemsetAsync(denom, 0, (size_t)BN_ * 4 * 4, stream);
  // zero the pad rows of xb (rows BN_..MPADL-1) read by gemm_lin A-loads
  hipMemsetAsync(xb + (size_t)BN_ * F_, 0, (size_t)(MPADL - BN_) * F_ * 2, stream);

  // conversions
  conv_wq_kernel<<<(MPADQ * S_ / 4 + 255) / 256, 256, 0, stream>>>(Wq, Wq_b);
  conv_xeT_kernel<<<(B_ * S_ * D_ + 255) / 256, 256, 0, stream>>>(x_enc, xeT);
  conv_bf16_kernel<<<(F_ * D_ / 4 + 255) / 256, 256, 0, stream>>>(Wlin, WlinB, F_ * D_ / 4);
  conv_bf16_kernel<<<(S_ * N_ / 4 + 255) / 256, 256, 0, stream>>>(Wproj, WprojB, S_ * N_ / 4);

  // CSR skeleton (independent of GEMMs)
  count_kernel<<<(2 * E_ + 255) / 256, 256, 0, stream>>>(ei, counts);
  scan_kernel<<<1, 1024, 0, stream>>>(counts, offsb, cursor);

  // gemm_q: x[b,n,d] = Wq·xe + bq + mask*Wm + bm   (bf16 MFMA)
  mfma_gemm_nt<1><<<dim3(MPADQ / 128, F_ / 128, B_), 256, 0, stream>>>(
      Wq_b, xeT, xb, S_, N_, (size_t)D_ * S_, (size_t)N_ * F_,
      bq, mask, Wm, bm);
  // gemm_lin: xp = x·Wlin^T   (bf16 MFMA)
  mfma_gemm_nt<0><<<dim3(MPADL / 128, F_ / 128, 1), 256, 0, stream>>>(
      xb, WlinB, xp, D_, BN_, 0, 0, nullptr, nullptr, nullptr, nullptr);

  att_kernel<<<(BN_ * H_ + 3) / 4, 256, 0, stream>>>(xp, att_src, att_dst, a_src, a_dst);
  fill_kernel<<<(ETOT_ + 255) / 256, 256, 0, stream>>>(ei, a_src, a_dst, cursor, col,
                                                       ealpha, denom);
  agg_kernel<<<BN_, 384, 0, stream>>>(offsb, cursor, col, ealpha, denom, xp, bias_gat, gat);
  transpose_kernel<<<dim3((N_ + TT - 1) / TT, F_ / TT, B_), 256, 0, stream>>>(gat, gatT);
  gemm_proj_mfma<<<dim3(S_ / 128, F_ / 128, B_ * PNS), 256, 0, stream>>>(WprojB, gatT, Ppart);
  temp_kernel<<<B_ * S_, 128, 0, stream>>>(Ppart, bproj, Wtemp, btemp, outp);
}

// Round 5
// 548.372 us; speedup vs baseline: 2.4369x; 1.1739x over previous
//
#include <hip/hip_runtime.h>
#include <hip/hip_bf16.h>
#include <cstdint>

// Problem constants
#define B_   2
#define S_   512
#define N_   20000
#define H_   3
#define C_   128
#define E_   320000
#define DG_  128
#define D_   384
#define BN_  (B_ * N_)            // 40000
#define F_   (H_ * C_)            // 384
#define ETOT_ (B_ * E_ + BN_)     // 680000

#define MPADQ 20096               // N_ padded to 128
#define MPADL 40064               // BN_ padded to 128

// split-K for proj GEMM (K = N_ = 20000 = 625 * 32)
#define PNS 20
#define PCHUNK 1024               // 32 k-iters per split (last split: 544)

using short8  = __attribute__((ext_vector_type(8))) short;
using floatx4 = __attribute__((ext_vector_type(4))) float;

// ================= conversion kernels =================
struct bf4 { __hip_bfloat16 a, b, c, d; };

__global__ __launch_bounds__(256) void conv_wq_kernel(const float* __restrict__ Wq,
                                                      __hip_bfloat16* __restrict__ o) {
  int idx = blockIdx.x * 256 + threadIdx.x;   // over MPADQ*512/4
  if (idx >= (MPADQ * 512) / 4) return;
  int e = idx * 4;
  int row = e >> 9;
  float4 v = make_float4(0.f, 0.f, 0.f, 0.f);
  if (row < N_) v = *(const float4*)(Wq + e);
  bf4 r{__float2bfloat16(v.x), __float2bfloat16(v.y),
        __float2bfloat16(v.z), __float2bfloat16(v.w)};
  *(bf4*)(o + e) = r;
}

// xe [B][S][D] fp32 -> xeT [B][D][S] bf16
__global__ __launch_bounds__(256) void conv_xeT_kernel(const float* __restrict__ xe,
                                                       __hip_bfloat16* __restrict__ o) {
  int idx = blockIdx.x * 256 + threadIdx.x;
  if (idx >= B_ * S_ * D_) return;
  int s = idx & 511;
  int rest = idx >> 9;
  int d = rest % D_;
  int b = rest / D_;
  o[idx] = __float2bfloat16(xe[(size_t)b * S_ * D_ + (size_t)s * D_ + d]);
}

// generic fp32 -> bf16 (length multiple of 4)
__global__ __launch_bounds__(256) void conv_bf16_kernel(const float* __restrict__ W,
                                                        __hip_bfloat16* __restrict__ o,
                                                        int n4) {
  int idx = blockIdx.x * 256 + threadIdx.x;
  if (idx >= n4) return;
  int e = idx * 4;
  float4 v = *(const float4*)(W + e);
  bf4 r{__float2bfloat16(v.x), __float2bfloat16(v.y),
        __float2bfloat16(v.z), __float2bfloat16(v.w)};
  *(bf4*)(o + e) = r;
}

// ================= bf16 MFMA GEMM (NT: A[m][k], Bt[n][k], both k-major) =================
template <int EPI>
__global__ __launch_bounds__(256) void mfma_gemm_nt(
    const __hip_bfloat16* __restrict__ A, const __hip_bfloat16* __restrict__ Bt,
    __hip_bfloat16* __restrict__ Cout, int K, int Mvalid,
    size_t bstrideB, size_t bstrideC,
    const float* __restrict__ bq, const float* __restrict__ mask,
    const float* __restrict__ Wm, const float* __restrict__ bm) {
  const int tid = threadIdx.x;
  const int m0 = blockIdx.x * 128;
  const int n0 = blockIdx.y * 128;
  const int bz = blockIdx.z;

  const unsigned short* Ap = (const unsigned short*)A;
  const unsigned short* Bp = (const unsigned short*)(Bt + bstrideB * bz);

  __shared__ __align__(16) unsigned short As[128][40];
  __shared__ __align__(16) unsigned short Bs[128][40];

  const int wave = tid >> 6, lane = tid & 63;
  const int wm = (wave & 1) * 64, wn = (wave >> 1) * 64;
  const int lrow = lane & 15, lk = (lane >> 4) * 8;

  const int srow = tid >> 2;            // 0..63
  const int skoff = (tid & 3) * 8;      // 0,8,16,24

  floatx4 acc[4][4];
#pragma unroll
  for (int i = 0; i < 4; ++i)
#pragma unroll
    for (int j = 0; j < 4; ++j) acc[i][j] = floatx4{0.f, 0.f, 0.f, 0.f};

  for (int k0 = 0; k0 < K; k0 += 32) {
    int4 av0 = *(const int4*)(Ap + (size_t)(m0 + srow) * K + k0 + skoff);
    int4 av1 = *(const int4*)(Ap + (size_t)(m0 + 64 + srow) * K + k0 + skoff);
    int4 bv0 = *(const int4*)(Bp + (size_t)(n0 + srow) * K + k0 + skoff);
    int4 bv1 = *(const int4*)(Bp + (size_t)(n0 + 64 + srow) * K + k0 + skoff);
    __syncthreads();
    *(int4*)&As[srow][skoff] = av0;
    *(int4*)&As[64 + srow][skoff] = av1;
    *(int4*)&Bs[srow][skoff] = bv0;
    *(int4*)&Bs[64 + srow][skoff] = bv1;
    __syncthreads();
    short8 af[4], bf[4];
#pragma unroll
    for (int mt = 0; mt < 4; ++mt)
      af[mt] = *(const short8*)&As[wm + mt * 16 + lrow][lk];
#pragma unroll
    for (int nt = 0; nt < 4; ++nt)
      bf[nt] = *(const short8*)&Bs[wn + nt * 16 + lrow][lk];
#pragma unroll
    for (int mt = 0; mt < 4; ++mt)
#pragma unroll
      for (int nt = 0; nt < 4; ++nt)
        acc[mt][nt] = __builtin_amdgcn_mfma_f32_16x16x32_bf16(af[mt], bf[nt],
                                                              acc[mt][nt], 0, 0, 0);
  }

  __hip_bfloat16* Cb = Cout + bstrideC * bz;
#pragma unroll
  for (int mt = 0; mt < 4; ++mt) {
#pragma unroll
    for (int r = 0; r < 4; ++r) {
      int rg = m0 + wm + mt * 16 + (lane >> 4) * 4 + r;
      if (rg < Mvalid) {
        float bqv = 0.f, mkv = 0.f;
        if (EPI) {
          bqv = bq[rg];
          mkv = mask[bz * N_ + rg];
        }
#pragma unroll
        for (int nt = 0; nt < 4; ++nt) {
          int cg = n0 + wn + nt * 16 + lrow;
          float v = acc[mt][nt][r];
          if (EPI) v += bqv + mkv * Wm[cg] + bm[cg];
          Cb[(size_t)rg * F_ + cg] = __float2bfloat16(v);
        }
      }
    }
  }
}

// ================= proj GEMM: split-K bf16 MFMA, fp32 partial output =================
__global__ __launch_bounds__(256) void gemm_proj_mfma(
    const __hip_bfloat16* __restrict__ A, const __hip_bfloat16* __restrict__ Bt,
    float* __restrict__ Ppart) {
  const int tid = threadIdx.x;
  const int m0 = blockIdx.x * 128;       // s
  const int n0 = blockIdx.y * 128;       // f
  const int bz = blockIdx.z;             // b*PNS + ks
  const int b = bz / PNS, ks = bz - b * PNS;
  const int kbeg = ks * PCHUNK;
  const int kend = (kbeg + PCHUNK < N_) ? (kbeg + PCHUNK) : N_;

  const unsigned short* Ap = (const unsigned short*)A;
  const unsigned short* Bp = (const unsigned short*)(Bt + (size_t)b * F_ * N_);

  __shared__ __align__(16) unsigned short As[128][40];
  __shared__ __align__(16) unsigned short Bs[128][40];

  const int wave = tid >> 6, lane = tid & 63;
  const int wm = (wave & 1) * 64, wn = (wave >> 1) * 64;
  const int lrow = lane & 15, lk = (lane >> 4) * 8;
  const int srow = tid >> 2;
  const int skoff = (tid & 3) * 8;

  floatx4 acc[4][4];
#pragma unroll
  for (int i = 0; i < 4; ++i)
#pragma unroll
    for (int j = 0; j < 4; ++j) acc[i][j] = floatx4{0.f, 0.f, 0.f, 0.f};

  for (int k0 = kbeg; k0 < kend; k0 += 32) {
    int4 av0 = *(const int4*)(Ap + (size_t)(m0 + srow) * N_ + k0 + skoff);
    int4 av1 = *(const int4*)(Ap + (size_t)(m0 + 64 + srow) * N_ + k0 + skoff);
    int4 bv0 = *(const int4*)(Bp + (size_t)(n0 + srow) * N_ + k0 + skoff);
    int4 bv1 = *(const int4*)(Bp + (size_t)(n0 + 64 + srow) * N_ + k0 + skoff);
    __syncthreads();
    *(int4*)&As[srow][skoff] = av0;
    *(int4*)&As[64 + srow][skoff] = av1;
    *(int4*)&Bs[srow][skoff] = bv0;
    *(int4*)&Bs[64 + srow][skoff] = bv1;
    __syncthreads();
    short8 af[4], bf[4];
#pragma unroll
    for (int mt = 0; mt < 4; ++mt)
      af[mt] = *(const short8*)&As[wm + mt * 16 + lrow][lk];
#pragma unroll
    for (int nt = 0; nt < 4; ++nt)
      bf[nt] = *(const short8*)&Bs[wn + nt * 16 + lrow][lk];
#pragma unroll
    for (int mt = 0; mt < 4; ++mt)
#pragma unroll
      for (int nt = 0; nt < 4; ++nt)
        acc[mt][nt] = __builtin_amdgcn_mfma_f32_16x16x32_bf16(af[mt], bf[nt],
                                                              acc[mt][nt], 0, 0, 0);
  }

  float* Pp = Ppart + (size_t)bz * S_ * F_;
#pragma unroll
  for (int mt = 0; mt < 4; ++mt) {
#pragma unroll
    for (int r = 0; r < 4; ++r) {
      int rg = m0 + wm + mt * 16 + (lane >> 4) * 4 + r;
#pragma unroll
      for (int nt = 0; nt < 4; ++nt) {
        int cg = n0 + wn + nt * 16 + lrow;
        Pp[(size_t)rg * F_ + cg] = acc[mt][nt][r];
      }
    }
  }
}

// ================= transpose gat [b][N][F] bf16 -> gatT [b][F][N] bf16 =================
#define TT 64
__global__ __launch_bounds__(256) void transpose_kernel(
    const __hip_bfloat16* __restrict__ in, __hip_bfloat16* __restrict__ out) {
  __shared__ unsigned short tile[TT][TT + 8];
  int n0 = blockIdx.x * TT, f0 = blockIdx.y * TT, b = blockIdx.z;
  int t = threadIdx.x;
  const unsigned short* ip = (const unsigned short*)(in + (size_t)b * N_ * F_);
  unsigned short* op = (unsigned short*)(out + (size_t)b * F_ * N_);
  int fo = (t & 7) * 8, ro = t >> 3;  // ro 0..31
#pragma unroll
  for (int half = 0; half < 2; ++half) {
    int r = ro + half * 32;
    if (n0 + r < N_)
      *(int4*)&tile[r][fo] = *(const int4*)(ip + (size_t)(n0 + r) * F_ + f0 + fo);
    else
      *(int4*)&tile[r][fo] = make_int4(0, 0, 0, 0);
  }
  __syncthreads();
  int no = (t & 7) * 8, fo2 = t >> 3;
  if (n0 + no + 8 <= N_) {
#pragma unroll
    for (int half = 0; half < 2; ++half) {
      int f = fo2 + half * 32;
      unsigned short v[8];
#pragma unroll
      for (int j = 0; j < 8; ++j) v[j] = tile[no + j][f];
      *(int4*)(op + (size_t)(f0 + f) * N_ + n0 + no) = *(int4*)v;
    }
  }
}

// ---------------- attention coefficients ----------------
__global__ __launch_bounds__(256) void att_kernel(
    const __hip_bfloat16* __restrict__ xp, const float* __restrict__ att_src,
    const float* __restrict__ att_dst, float* __restrict__ a_src,
    float* __restrict__ a_dst) {
  int gid = blockIdx.x * blockDim.x + threadIdx.x;
  int wid = gid >> 6;
  int lane = threadIdx.x & 63;
  if (wid >= BN_ * H_) return;
  int i = wid / H_, h = wid - i * H_;
  const __hip_bfloat16* row = xp + (size_t)i * F_ + h * C_;
  const float* as = att_src + h * C_;
  const float* ad = att_dst + h * C_;
  float v0 = __bfloat162float(row[lane]), v1 = __bfloat162float(row[lane + 64]);
  float s1 = v0 * as[lane] + v1 * as[lane + 64];
  float s2 = v0 * ad[lane] + v1 * ad[lane + 64];
#pragma unroll
  for (int off = 32; off > 0; off >>= 1) {
    s1 += __shfl_down(s1, off);
    s2 += __shfl_down(s2, off);
  }
  if (lane == 0) {
    a_src[i * H_ + h] = s1;
    a_dst[i * H_ + h] = s2;
  }
}

// ---------------- CSR build ----------------
// counts + per-edge rank (atomicAdd return value), rank written coalesced
__global__ __launch_bounds__(256) void count_kernel(const int* __restrict__ ei,
                                                    int* __restrict__ counts,
                                                    int* __restrict__ rank) {
  int idx = blockIdx.x * blockDim.x + threadIdx.x;
  if (idx >= 2 * E_) return;
  int b = (idx >= E_) ? 1 : 0;
  int e = idx - b * E_;
  int d = ei[E_ + e];
  rank[idx] = atomicAdd(&counts[b * N_ + d], 1);
}

// single-block shuffle-based exclusive scan of (counts[i]+1)
__global__ __launch_bounds__(1024) void scan_kernel(const int* __restrict__ counts,
                                                    int* __restrict__ offs) {
  __shared__ int wsum[16];
  __shared__ int carry;
  int t = threadIdx.x, wave = t >> 6, lane = t & 63;
  if (t == 0) carry = 0;
  __syncthreads();
  for (int base = 0; base < BN_; base += 1024) {
    int i = base + t;
    int v = (i < BN_) ? (counts[i] + 1) : 0;  // +1 = self loop
    int x = v;
#pragma unroll
    for (int o = 1; o < 64; o <<= 1) {
      int y = __shfl_up(x, o);
      if (lane >= o) x += y;
    }
    if (lane == 63) wsum[wave] = x;
    __syncthreads();
    int c = carry;
    if (wave == 0) {
      int w = (lane < 16) ? wsum[lane] : 0;
#pragma unroll
      for (int o = 1; o < 16; o <<= 1) {
        int y = __shfl_up(w, o);
        if (lane >= o) w += y;
      }
      if (lane < 16) wsum[lane] = w;
    }
    __syncthreads();
    int woff = (wave == 0) ? 0 : wsum[wave - 1];
    int excl = c + woff + x - v;
    if (i < BN_) offs[i] = excl;
    int total = wsum[15];
    __syncthreads();
    if (t == 0) carry = c + total;
  }
}

// fill CSR col — NO atomics: pos = offs[dst] + rank[edge]; self-loop at offs[i]+counts[i]
__global__ __launch_bounds__(256) void fill_kernel(
    const int* __restrict__ ei, const int* __restrict__ rank,
    const int* __restrict__ offs, const int* __restrict__ counts,
    int* __restrict__ col) {
  int idx = blockIdx.x * blockDim.x + threadIdx.x;
  if (idx >= ETOT_) return;
  if (idx < 2 * E_) {
    int b = (idx >= E_) ? 1 : 0;
    int e = idx - b * E_;
    int sg = b * N_ + ei[e];
    int dg = b * N_ + ei[E_ + e];
    col[offs[dg] + rank[idx]] = sg;
  } else {
    int i = idx - 2 * E_;
    col[offs[i] + counts[i]] = i;
  }
}

// ---------------- aggregation: single pass; exp staged in LDS; denom in-block ----------------
#define CHK 64
__global__ __launch_bounds__(384) void agg_kernel(
    const int* __restrict__ offs, const int* __restrict__ counts,
    const int* __restrict__ col, const float* __restrict__ a_src,
    const float* __restrict__ a_dst, const __hip_bfloat16* __restrict__ xp,
    const float* __restrict__ bias_gat, __hip_bfloat16* __restrict__ out) {
  int i = blockIdx.x;
  int t = threadIdx.x;
  int h = t >> 7;        // head (C=128)
  int beg = offs[i];
  int nE = counts[i] + 1;
  __shared__ int scol[CHK];
  __shared__ float sexp[CHK][4];
  __shared__ float sden[CHK][4];
  __shared__ float sdenf[4];

  float ad0 = a_dst[i * H_ + 0], ad1 = a_dst[i * H_ + 1], ad2 = a_dst[i * H_ + 2];
  float d0 = 0.f, d1 = 0.f, d2 = 0.f;   // per-stager denominator partials

  float a0 = 0.f, a1 = 0.f;
  for (int c0 = 0; c0 < nE; c0 += CHK) {
    int cn = min(CHK, nE - c0);
    __syncthreads();
    if (t < cn) {
      int s = col[beg + c0 + t];
      scol[t] = s;
      float e0 = a_src[s * H_ + 0] + ad0;
      float e1 = a_src[s * H_ + 1] + ad1;
      float e2 = a_src[s * H_ + 2] + ad2;
      e0 = (e0 > 0.f) ? e0 : 0.2f * e0;
      e1 = (e1 > 0.f) ? e1 : 0.2f * e1;
      e2 = (e2 > 0.f) ? e2 : 0.2f * e2;
      float x0 = __expf(e0), x1 = __expf(e1), x2 = __expf(e2);
      sexp[t][0] = x0; sexp[t][1] = x1; sexp[t][2] = x2;
      d0 += x0; d1 += x1; d2 += x2;
    }
    __syncthreads();
    int j = 0;
    for (; j + 8 <= cn; j += 8) {
      int s0 = scol[j + 0], s1 = scol[j + 1], s2 = scol[j + 2], s3 = scol[j + 3];
      int s4 = scol[j + 4], s5 = scol[j + 5], s6 = scol[j + 6], s7 = scol[j + 7];
      float x0 = __bfloat162float(xp[(size_t)s0 * F_ + t]);
      float x1 = __bfloat162float(xp[(size_t)s1 * F_ + t]);
      float x2 = __bfloat162float(xp[(size_t)s2 * F_ + t]);
      float x3 = __bfloat162float(xp[(size_t)s3 * F_ + t]);
      float x4 = __bfloat162float(xp[(size_t)s4 * F_ + t]);
      float x5 = __bfloat162float(xp[(size_t)s5 * F_ + t]);
      float x6 = __bfloat162float(xp[(size_t)s6 * F_ + t]);
      float x7 = __bfloat162float(xp[(size_t)s7 * F_ + t]);
      a0 = fmaf(sexp[j + 0][h], x0, a0);
      a1 = fmaf(sexp[j + 1][h], x1, a1);
      a0 = fmaf(sexp[j + 2][h], x2, a0);
      a1 = fmaf(sexp[j + 3][h], x3, a1);
      a0 = fmaf(sexp[j + 4][h], x4, a0);
      a1 = fmaf(sexp[j + 5][h], x5, a1);
      a0 = fmaf(sexp[j + 6][h], x6, a0);
      a1 = fmaf(sexp[j + 7][h], x7, a1);
    }
    for (; j < cn; ++j) {
      a0 = fmaf(sexp[j][h], __bfloat162float(xp[(size_t)scol[j] * F_ + t]), a0);
    }
  }
  // block-level denominator reduction (stagers t<64 hold partials)
  if (t < CHK) { sden[t][0] = d0; sden[t][1] = d1; sden[t][2] = d2; }
  __syncthreads();
  if (t < 32) {
#pragma unroll
    for (int c = 0; c < 3; ++c) sden[t][c] += sden[t + 32][c];
  }
  __syncthreads();
  if (t < 3) {
    float s = 0.f;
#pragma unroll
    for (int j = 0; j < 32; ++j) s += sden[j][t];
    sdenf[t] = 1.0f / s;
  }
  __syncthreads();
  out[(size_t)i * F_ + t] = __float2bfloat16((a0 + a1) * sdenf[h] + bias_gat[t]);
}

// ---------------- GEMM 4: reduce split-K partials + temp projection ----------------
__global__ __launch_bounds__(128) void temp_kernel(
    const float* __restrict__ Ppart, const float* __restrict__ bproj,
    const float* __restrict__ Wtemp, const float* __restrict__ btemp,
    float* __restrict__ out) {
  int bs = blockIdx.x;          // 0..B*S-1
  int b = bs >> 9;
  int s = bs & (S_ - 1);
  int g = threadIdx.x;
  __shared__ float prow[F_];
  float bp = bproj[s];
  for (int f = g; f < F_; f += 128) {
    float acc = bp;
    const float* pp = Ppart + ((size_t)b * PNS * S_ + s) * F_ + f;
    for (int ns = 0; ns < PNS; ++ns) acc += pp[(size_t)ns * S_ * F_];
    prow[f] = acc;
  }
  __syncthreads();
  float acc = btemp[g];
  const float* w = Wtemp + (size_t)g * F_;
  for (int f = 0; f < F_; f += 4) {
    float4 pv = *(const float4*)&prow[f];
    float4 wv = *(const float4*)&w[f];
    acc += pv.x * wv.x + pv.y * wv.y + pv.z * wv.z + pv.w * wv.w;
  }
  out[(size_t)bs * DG_ + g] = acc;
}

// ---------------- launcher ----------------
extern "C" void kernel_launch(void* const* d_in, const int* in_sizes, int n_in,
                              void* d_out, int out_size, void* d_ws, size_t ws_size,
                              hipStream_t stream) {
  const float* x_enc   = (const float*)d_in[0];
  const float* mask    = (const float*)d_in[1];
  const int*   ei      = (const int*)d_in[2];
  const float* Wq      = (const float*)d_in[3];
  const float* bq      = (const float*)d_in[4];
  const float* Wm      = (const float*)d_in[5];
  const float* bm      = (const float*)d_in[6];
  const float* Wlin    = (const float*)d_in[7];
  const float* att_src = (const float*)d_in[8];
  const float* att_dst = (const float*)d_in[9];
  const float* bias_gat= (const float*)d_in[10];
  const float* Wproj   = (const float*)d_in[11];
  const float* bproj   = (const float*)d_in[12];
  const float* Wtemp   = (const float*)d_in[13];
  const float* btemp   = (const float*)d_in[14];
  float* outp = (float*)d_out;

  char* ws = (char*)d_ws;
  size_t off = 0;
  auto alloc = [&](size_t bytes) {
    char* p = ws + off;
    off = (off + bytes + 255) & ~(size_t)255;
    return p;
  };

  // regionA timeline:
  //   phase 1 (conv/gemm_q/gemm_lin): Wq_b + xeT + xb
  //   phase 2 (agg):                  gat bf16 at 0..30.7M
  //   phase 3 (transpose):            gatT at 31.46..62.2M (reads gat)
  //   phase 4 (gemm_proj):            Ppart fp32 at 0..31.46M (reads gatT)
  const size_t GATT_OFF = 31457536;  // > Ppart end (31,457,280), 256-aligned
  char* regionA = alloc(GATT_OFF + (size_t)B_ * F_ * N_ * 2);   // 62.2 MB
  __hip_bfloat16* Wq_b = (__hip_bfloat16*)regionA;
  __hip_bfloat16* xeT  = (__hip_bfloat16*)(regionA + (size_t)MPADQ * S_ * 2);
  __hip_bfloat16* xb   = (__hip_bfloat16*)(regionA + (size_t)MPADQ * S_ * 2
                                                   + (size_t)B_ * D_ * S_ * 2);
  __hip_bfloat16* gat  = (__hip_bfloat16*)regionA;
  __hip_bfloat16* gatT = (__hip_bfloat16*)(regionA + GATT_OFF);
  float* Ppart = (float*)regionA;

  __hip_bfloat16* xp     = (__hip_bfloat16*)alloc((size_t)BN_ * F_ * 2);
  __hip_bfloat16* WlinB  = (__hip_bfloat16*)alloc((size_t)F_ * D_ * 2);
  __hip_bfloat16* WprojB = (__hip_bfloat16*)alloc((size_t)S_ * N_ * 2);
  float* a_src = (float*)alloc((size_t)BN_ * H_ * 4);
  float* a_dst = (float*)alloc((size_t)BN_ * H_ * 4);
  int* counts  = (int*)alloc((size_t)BN_ * 4);
  int* offsb   = (int*)alloc((size_t)BN_ * 4);
  int* rank    = (int*)alloc((size_t)2 * E_ * 4);
  int* col     = (int*)alloc((size_t)ETOT_ * 4);
  if (off > ws_size) return;  // workspace too small: fail loudly via absmax

  hipMemsetAsync(counts, 0, (size_t)BN_ * 4, stream);
  // zero the pad rows of xb (rows BN_..MPADL-1) read by gemm_lin A-loads
  hipMemsetAsync(xb + (size_t)BN_ * F_, 0, (size_t)(MPADL - BN_) * F_ * 2, stream);

  // CSR skeleton (independent of everything else)
  count_kernel<<<(2 * E_ + 255) / 256, 256, 0, stream>>>(ei, counts, rank);
  scan_kernel<<<1, 1024, 0, stream>>>(counts, offsb);
  fill_kernel<<<(ETOT_ + 255) / 256, 256, 0, stream>>>(ei, rank, offsb, counts, col);

  // conversions
  conv_wq_kernel<<<(MPADQ * S_ / 4 + 255) / 256, 256, 0, stream>>>(Wq, Wq_b);
  conv_xeT_kernel<<<(B_ * S_ * D_ + 255) / 256, 256, 0, stream>>>(x_enc, xeT);
  conv_bf16_kernel<<<(F_ * D_ / 4 + 255) / 256, 256, 0, stream>>>(Wlin, WlinB, F_ * D_ / 4);
  conv_bf16_kernel<<<(S_ * N_ / 4 + 255) / 256, 256, 0, stream>>>(Wproj, WprojB, S_ * N_ / 4);

  // gemm_q: x[b,n,d] = Wq·xe + bq + mask*Wm + bm   (bf16 MFMA)
  mfma_gemm_nt<1><<<dim3(MPADQ / 128, F_ / 128, B_), 256, 0, stream>>>(
      Wq_b, xeT, xb, S_, N_, (size_t)D_ * S_, (size_t)N_ * F_,
      bq, mask, Wm, bm);
  // gemm_lin: xp = x·Wlin^T   (bf16 MFMA)
  mfma_gemm_nt<0><<<dim3(MPADL / 128, F_ / 128, 1), 256, 0, stream>>>(
      xb, WlinB, xp, D_, BN_, 0, 0, nullptr, nullptr, nullptr, nullptr);

  att_kernel<<<(BN_ * H_ + 3) / 4, 256, 0, stream>>>(xp, att_src, att_dst, a_src, a_dst);
  agg_kernel<<<BN_, 384, 0, stream>>>(offsb, counts, col, a_src, a_dst, xp, bias_gat, gat);
  transpose_kernel<<<dim3((N_ + TT - 1) / TT, F_ / TT, B_), 256, 0, stream>>>(gat, gatT);
  gemm_proj_mfma<<<dim3(S_ / 128, F_ / 128, B_ * PNS), 256, 0, stream>>>(WprojB, gatT, Ppart);
  temp_kernel<<<B_ * S_, 128, 0, stream>>>(Ppart, bproj, Wtemp, btemp, outp);
}

// Round 7
// 475.895 us; speedup vs baseline: 2.8080x; 1.1523x over previous
//
#include <hip/hip_runtime.h>
#include <hip/hip_bf16.h>
#include <cstdint>

// Problem constants
#define B_   2
#define S_   512
#define N_   20000
#define H_   3
#define C_   128
#define E_   320000
#define DG_  128
#define D_   384
#define BN_  (B_ * N_)            // 40000
#define F_   (H_ * C_)            // 384
#define ETOT_ (B_ * E_ + BN_)     // 680000

#define MPADQ 20096               // N_ padded to 128
#define MPADL 40064               // BN_ padded to 128

// split-K for proj GEMM (K = N_ = 20000 = 625 * 32)
#define PNS 20
#define PCHUNK 1024               // 32 k-iters per split (last split: 544)

using short8  = __attribute__((ext_vector_type(8))) short;
using floatx4 = __attribute__((ext_vector_type(4))) float;

__device__ __forceinline__ float b2f(unsigned short u) {
  union { unsigned int i; float f; } x; x.i = ((unsigned int)u) << 16; return x.f;
}
__device__ __forceinline__ unsigned short f2b(float f) {
  __hip_bfloat16 b = __float2bfloat16(f);
  return *reinterpret_cast<unsigned short*>(&b);
}

// ================= conversion kernels =================
struct bf4 { __hip_bfloat16 a, b, c, d; };

__global__ __launch_bounds__(256) void conv_wq_kernel(const float* __restrict__ Wq,
                                                      __hip_bfloat16* __restrict__ o) {
  int idx = blockIdx.x * 256 + threadIdx.x;   // over MPADQ*512/4
  if (idx >= (MPADQ * 512) / 4) return;
  int e = idx * 4;
  int row = e >> 9;
  float4 v = make_float4(0.f, 0.f, 0.f, 0.f);
  if (row < N_) v = *(const float4*)(Wq + e);
  bf4 r{__float2bfloat16(v.x), __float2bfloat16(v.y),
        __float2bfloat16(v.z), __float2bfloat16(v.w)};
  *(bf4*)(o + e) = r;
}

// xe [B][S][D] fp32 -> xeT [B][D][S] bf16
__global__ __launch_bounds__(256) void conv_xeT_kernel(const float* __restrict__ xe,
                                                       __hip_bfloat16* __restrict__ o) {
  int idx = blockIdx.x * 256 + threadIdx.x;
  if (idx >= B_ * S_ * D_) return;
  int s = idx & 511;
  int rest = idx >> 9;
  int d = rest % D_;
  int b = rest / D_;
  o[idx] = __float2bfloat16(xe[(size_t)b * S_ * D_ + (size_t)s * D_ + d]);
}

// generic fp32 -> bf16 (length multiple of 4)
__global__ __launch_bounds__(256) void conv_bf16_kernel(const float* __restrict__ W,
                                                        __hip_bfloat16* __restrict__ o,
                                                        int n4) {
  int idx = blockIdx.x * 256 + threadIdx.x;
  if (idx >= n4) return;
  int e = idx * 4;
  float4 v = *(const float4*)(W + e);
  bf4 r{__float2bfloat16(v.x), __float2bfloat16(v.y),
        __float2bfloat16(v.z), __float2bfloat16(v.w)};
  *(bf4*)(o + e) = r;
}

// ================= bf16 MFMA GEMM (NT: A[m][k], Bt[n][k], both k-major) =================
template <int EPI>
__global__ __launch_bounds__(256) void mfma_gemm_nt(
    const __hip_bfloat16* __restrict__ A, const __hip_bfloat16* __restrict__ Bt,
    __hip_bfloat16* __restrict__ Cout, int K, int Mvalid,
    size_t bstrideB, size_t bstrideC,
    const float* __restrict__ bq, const float* __restrict__ mask,
    const float* __restrict__ Wm, const float* __restrict__ bm) {
  const int tid = threadIdx.x;
  const int m0 = blockIdx.x * 128;
  const int n0 = blockIdx.y * 128;
  const int bz = blockIdx.z;

  const unsigned short* Ap = (const unsigned short*)A;
  const unsigned short* Bp = (const unsigned short*)(Bt + bstrideB * bz);

  __shared__ __align__(16) unsigned short As[128][40];
  __shared__ __align__(16) unsigned short Bs[128][40];

  const int wave = tid >> 6, lane = tid & 63;
  const int wm = (wave & 1) * 64, wn = (wave >> 1) * 64;
  const int lrow = lane & 15, lk = (lane >> 4) * 8;

  const int srow = tid >> 2;            // 0..63
  const int skoff = (tid & 3) * 8;      // 0,8,16,24

  floatx4 acc[4][4];
#pragma unroll
  for (int i = 0; i < 4; ++i)
#pragma unroll
    for (int j = 0; j < 4; ++j) acc[i][j] = floatx4{0.f, 0.f, 0.f, 0.f};

  for (int k0 = 0; k0 < K; k0 += 32) {
    int4 av0 = *(const int4*)(Ap + (size_t)(m0 + srow) * K + k0 + skoff);
    int4 av1 = *(const int4*)(Ap + (size_t)(m0 + 64 + srow) * K + k0 + skoff);
    int4 bv0 = *(const int4*)(Bp + (size_t)(n0 + srow) * K + k0 + skoff);
    int4 bv1 = *(const int4*)(Bp + (size_t)(n0 + 64 + srow) * K + k0 + skoff);
    __syncthreads();
    *(int4*)&As[srow][skoff] = av0;
    *(int4*)&As[64 + srow][skoff] = av1;
    *(int4*)&Bs[srow][skoff] = bv0;
    *(int4*)&Bs[64 + srow][skoff] = bv1;
    __syncthreads();
    short8 af[4], bf[4];
#pragma unroll
    for (int mt = 0; mt < 4; ++mt)
      af[mt] = *(const short8*)&As[wm + mt * 16 + lrow][lk];
#pragma unroll
    for (int nt = 0; nt < 4; ++nt)
      bf[nt] = *(const short8*)&Bs[wn + nt * 16 + lrow][lk];
#pragma unroll
    for (int mt = 0; mt < 4; ++mt)
#pragma unroll
      for (int nt = 0; nt < 4; ++nt)
        acc[mt][nt] = __builtin_amdgcn_mfma_f32_16x16x32_bf16(af[mt], bf[nt],
                                                              acc[mt][nt], 0, 0, 0);
  }

  __hip_bfloat16* Cb = Cout + bstrideC * bz;
#pragma unroll
  for (int mt = 0; mt < 4; ++mt) {
#pragma unroll
    for (int r = 0; r < 4; ++r) {
      int rg = m0 + wm + mt * 16 + (lane >> 4) * 4 + r;
      if (rg < Mvalid) {
        float bqv = 0.f, mkv = 0.f;
        if (EPI) {
          bqv = bq[rg];
          mkv = mask[bz * N_ + rg];
        }
#pragma unroll
        for (int nt = 0; nt < 4; ++nt) {
          int cg = n0 + wn + nt * 16 + lrow;
          float v = acc[mt][nt][r];
          if (EPI) v += bqv + mkv * Wm[cg] + bm[cg];
          Cb[(size_t)rg * F_ + cg] = __float2bfloat16(v);
        }
      }
    }
  }
}

// ================= proj GEMM: split-K bf16 MFMA, fp32 partial output =================
__global__ __launch_bounds__(256) void gemm_proj_mfma(
    const __hip_bfloat16* __restrict__ A, const __hip_bfloat16* __restrict__ Bt,
    float* __restrict__ Ppart) {
  const int tid = threadIdx.x;
  const int m0 = blockIdx.x * 128;       // s
  const int n0 = blockIdx.y * 128;       // f
  const int bz = blockIdx.z;             // b*PNS + ks
  const int b = bz / PNS, ks = bz - b * PNS;
  const int kbeg = ks * PCHUNK;
  const int kend = (kbeg + PCHUNK < N_) ? (kbeg + PCHUNK) : N_;

  const unsigned short* Ap = (const unsigned short*)A;
  const unsigned short* Bp = (const unsigned short*)(Bt + (size_t)b * F_ * N_);

  __shared__ __align__(16) unsigned short As[128][40];
  __shared__ __align__(16) unsigned short Bs[128][40];

  const int wave = tid >> 6, lane = tid & 63;
  const int wm = (wave & 1) * 64, wn = (wave >> 1) * 64;
  const int lrow = lane & 15, lk = (lane >> 4) * 8;
  const int srow = tid >> 2;
  const int skoff = (tid & 3) * 8;

  floatx4 acc[4][4];
#pragma unroll
  for (int i = 0; i < 4; ++i)
#pragma unroll
    for (int j = 0; j < 4; ++j) acc[i][j] = floatx4{0.f, 0.f, 0.f, 0.f};

  for (int k0 = kbeg; k0 < kend; k0 += 32) {
    int4 av0 = *(const int4*)(Ap + (size_t)(m0 + srow) * N_ + k0 + skoff);
    int4 av1 = *(const int4*)(Ap + (size_t)(m0 + 64 + srow) * N_ + k0 + skoff);
    int4 bv0 = *(const int4*)(Bp + (size_t)(n0 + srow) * N_ + k0 + skoff);
    int4 bv1 = *(const int4*)(Bp + (size_t)(n0 + 64 + srow) * N_ + k0 + skoff);
    __syncthreads();
    *(int4*)&As[srow][skoff] = av0;
    *(int4*)&As[64 + srow][skoff] = av1;
    *(int4*)&Bs[srow][skoff] = bv0;
    *(int4*)&Bs[64 + srow][skoff] = bv1;
    __syncthreads();
    short8 af[4], bf[4];
#pragma unroll
    for (int mt = 0; mt < 4; ++mt)
      af[mt] = *(const short8*)&As[wm + mt * 16 + lrow][lk];
#pragma unroll
    for (int nt = 0; nt < 4; ++nt)
      bf[nt] = *(const short8*)&Bs[wn + nt * 16 + lrow][lk];
#pragma unroll
    for (int mt = 0; mt < 4; ++mt)
#pragma unroll
      for (int nt = 0; nt < 4; ++nt)
        acc[mt][nt] = __builtin_amdgcn_mfma_f32_16x16x32_bf16(af[mt], bf[nt],
                                                              acc[mt][nt], 0, 0, 0);
  }

  float* Pp = Ppart + (size_t)bz * S_ * F_;
#pragma unroll
  for (int mt = 0; mt < 4; ++mt) {
#pragma unroll
    for (int r = 0; r < 4; ++r) {
      int rg = m0 + wm + mt * 16 + (lane >> 4) * 4 + r;
#pragma unroll
      for (int nt = 0; nt < 4; ++nt) {
        int cg = n0 + wn + nt * 16 + lrow;
        Pp[(size_t)rg * F_ + cg] = acc[mt][nt][r];
      }
    }
  }
}

// ================= transpose gat [b][N][F] bf16 -> gatT [b][F][N] bf16 =================
#define TT 64
__global__ __launch_bounds__(256) void transpose_kernel(
    const __hip_bfloat16* __restrict__ in, __hip_bfloat16* __restrict__ out) {
  __shared__ unsigned short tile[TT][TT + 8];
  int n0 = blockIdx.x * TT, f0 = blockIdx.y * TT, b = blockIdx.z;
  int t = threadIdx.x;
  const unsigned short* ip = (const unsigned short*)(in + (size_t)b * N_ * F_);
  unsigned short* op = (unsigned short*)(out + (size_t)b * F_ * N_);
  int fo = (t & 7) * 8, ro = t >> 3;  // ro 0..31
#pragma unroll
  for (int half = 0; half < 2; ++half) {
    int r = ro + half * 32;
    if (n0 + r < N_)
      *(int4*)&tile[r][fo] = *(const int4*)(ip + (size_t)(n0 + r) * F_ + f0 + fo);
    else
      *(int4*)&tile[r][fo] = make_int4(0, 0, 0, 0);
  }
  __syncthreads();
  int no = (t & 7) * 8, fo2 = t >> 3;
  if (n0 + no + 8 <= N_) {
#pragma unroll
    for (int half = 0; half < 2; ++half) {
      int f = fo2 + half * 32;
      unsigned short v[8];
#pragma unroll
      for (int j = 0; j < 8; ++j) v[j] = tile[no + j][f];
      *(int4*)(op + (size_t)(f0 + f) * N_ + n0 + no) = *(int4*)v;
    }
  }
}

// ---------------- attention coefficients ----------------
__global__ __launch_bounds__(256) void att_kernel(
    const __hip_bfloat16* __restrict__ xp, const float* __restrict__ att_src,
    const float* __restrict__ att_dst, float* __restrict__ a_src,
    float* __restrict__ a_dst) {
  int gid = blockIdx.x * blockDim.x + threadIdx.x;
  int wid = gid >> 6;
  int lane = threadIdx.x & 63;
  if (wid >= BN_ * H_) return;
  int i = wid / H_, h = wid - i * H_;
  const __hip_bfloat16* row = xp + (size_t)i * F_ + h * C_;
  const float* as = att_src + h * C_;
  const float* ad = att_dst + h * C_;
  float v0 = __bfloat162float(row[lane]), v1 = __bfloat162float(row[lane + 64]);
  float s1 = v0 * as[lane] + v1 * as[lane + 64];
  float s2 = v0 * ad[lane] + v1 * ad[lane + 64];
#pragma unroll
  for (int off = 32; off > 0; off >>= 1) {
    s1 += __shfl_down(s1, off);
    s2 += __shfl_down(s2, off);
  }
  if (lane == 0) {
    a_src[i * H_ + h] = s1;
    a_dst[i * H_ + h] = s2;
  }
}

// ---------------- CSR build ----------------
// counts + per-edge rank (atomicAdd return value), rank written coalesced
__global__ __launch_bounds__(256) void count_kernel(const int* __restrict__ ei,
                                                    int* __restrict__ counts,
                                                    int* __restrict__ rank) {
  int idx = blockIdx.x * blockDim.x + threadIdx.x;
  if (idx >= 2 * E_) return;
  int b = (idx >= E_) ? 1 : 0;
  int e = idx - b * E_;
  int d = ei[E_ + e];
  rank[idx] = atomicAdd(&counts[b * N_ + d], 1);
}

// single-block shuffle-based exclusive scan of (counts[i]+1)
__global__ __launch_bounds__(1024) void scan_kernel(const int* __restrict__ counts,
                                                    int* __restrict__ offs) {
  __shared__ int wsum[16];
  __shared__ int carry;
  int t = threadIdx.x, wave = t >> 6, lane = t & 63;
  if (t == 0) carry = 0;
  __syncthreads();
  for (int base = 0; base < BN_; base += 1024) {
    int i = base + t;
    int v = (i < BN_) ? (counts[i] + 1) : 0;  // +1 = self loop
    int x = v;
#pragma unroll
    for (int o = 1; o < 64; o <<= 1) {
      int y = __shfl_up(x, o);
      if (lane >= o) x += y;
    }
    if (lane == 63) wsum[wave] = x;
    __syncthreads();
    int c = carry;
    if (wave == 0) {
      int w = (lane < 16) ? wsum[lane] : 0;
#pragma unroll
      for (int o = 1; o < 16; o <<= 1) {
        int y = __shfl_up(w, o);
        if (lane >= o) w += y;
      }
      if (lane < 16) wsum[lane] = w;
    }
    __syncthreads();
    int woff = (wave == 0) ? 0 : wsum[wave - 1];
    int excl = c + woff + x - v;
    if (i < BN_) offs[i] = excl;
    int total = wsum[15];
    __syncthreads();
    if (t == 0) carry = c + total;
  }
}

// fill CSR col — NO atomics: pos = offs[dst] + rank[edge]; self-loop at offs[i]+counts[i]
__global__ __launch_bounds__(256) void fill_kernel(
    const int* __restrict__ ei, const int* __restrict__ rank,
    const int* __restrict__ offs, const int* __restrict__ counts,
    int* __restrict__ col) {
  int idx = blockIdx.x * blockDim.x + threadIdx.x;
  if (idx >= ETOT_) return;
  if (idx < 2 * E_) {
    int b = (idx >= E_) ? 1 : 0;
    int e = idx - b * E_;
    int sg = b * N_ + ei[e];
    int dg = b * N_ + ei[E_ + e];
    col[offs[dg] + rank[idx]] = sg;
  } else {
    int i = idx - 2 * E_;
    col[offs[i] + counts[i]] = i;
  }
}

// ---------------- per-node softmax denominators (wave per node) ----------------
__global__ __launch_bounds__(256) void denom_kernel(
    const int* __restrict__ offs, const int* __restrict__ counts,
    const int* __restrict__ col, const float* __restrict__ a_src,
    const float* __restrict__ a_dst, float4* __restrict__ rden4) {
  int i = (blockIdx.x * 256 + threadIdx.x) >> 6;   // global wave id = node
  int lane = threadIdx.x & 63;
  if (i >= BN_) return;                            // wave-uniform
  int beg = offs[i], nE = counts[i] + 1;
  float ad0 = a_dst[i * 3 + 0], ad1 = a_dst[i * 3 + 1], ad2 = a_dst[i * 3 + 2];
  float d0 = 0.f, d1 = 0.f, d2 = 0.f;
  for (int j = lane; j < nE; j += 64) {
    int s = col[beg + j];
    float e0 = a_src[s * 3 + 0] + ad0;
    float e1 = a_src[s * 3 + 1] + ad1;
    float e2 = a_src[s * 3 + 2] + ad2;
    e0 = (e0 > 0.f) ? e0 : 0.2f * e0;
    e1 = (e1 > 0.f) ? e1 : 0.2f * e1;
    e2 = (e2 > 0.f) ? e2 : 0.2f * e2;
    d0 += __expf(e0); d1 += __expf(e1); d2 += __expf(e2);
  }
#pragma unroll
  for (int o = 32; o > 0; o >>= 1) {
    d0 += __shfl_down(d0, o);
    d1 += __shfl_down(d1, o);
    d2 += __shfl_down(d2, o);
  }
  if (lane == 0) rden4[i] = make_float4(1.0f / d0, 1.0f / d1, 1.0f / d2, 0.f);
}

// ---------------- aggregation: 128 threads; 96 gather ushort4, 32 stage ----------------
// denominators precomputed (rden4) — agg is a pure weighted gather.
#define ACHK 32
__global__ __launch_bounds__(128) void agg_kernel(
    const int* __restrict__ offs, const int* __restrict__ counts,
    const int* __restrict__ col, const float* __restrict__ a_src,
    const float* __restrict__ a_dst, const float4* __restrict__ rden4,
    const __hip_bfloat16* __restrict__ xp,
    const float* __restrict__ bias_gat, __hip_bfloat16* __restrict__ out) {
  int i = blockIdx.x;
  int t = threadIdx.x;
  int beg = offs[i];
  int nE = counts[i] + 1;
  __shared__ int scol[ACHK];
  __shared__ float sexp[ACHK][4];

  const ushort4* xp4 = (const ushort4*)xp;   // row stride 96 ushort4
  int h = t >> 5;                            // head for gather threads (t<96)
  float ax = 0.f, ay = 0.f, az = 0.f, aw = 0.f;
  float ad0 = 0.f, ad1 = 0.f, ad2 = 0.f;
  if (t >= 96) {
    ad0 = a_dst[i * 3 + 0]; ad1 = a_dst[i * 3 + 1]; ad2 = a_dst[i * 3 + 2];
  }

  for (int c0 = 0; c0 < nE; c0 += ACHK) {
    int cn = min(ACHK, nE - c0);
    __syncthreads();
    int ts = t - 96;
    if (ts >= 0 && ts < cn) {
      int s = col[beg + c0 + ts];
      scol[ts] = s;
      float e0 = a_src[s * 3 + 0] + ad0;
      float e1 = a_src[s * 3 + 1] + ad1;
      float e2 = a_src[s * 3 + 2] + ad2;
      e0 = (e0 > 0.f) ? e0 : 0.2f * e0;
      e1 = (e1 > 0.f) ? e1 : 0.2f * e1;
      e2 = (e2 > 0.f) ? e2 : 0.2f * e2;
      sexp[ts][0] = __expf(e0);
      sexp[ts][1] = __expf(e1);
      sexp[ts][2] = __expf(e2);
    }
    __syncthreads();
    if (t < 96) {
      int j = 0;
      for (; j + 4 <= cn; j += 4) {
        int s0 = scol[j + 0], s1 = scol[j + 1], s2 = scol[j + 2], s3 = scol[j + 3];
        ushort4 v0 = xp4[(size_t)s0 * 96 + t];
        ushort4 v1 = xp4[(size_t)s1 * 96 + t];
        ushort4 v2 = xp4[(size_t)s2 * 96 + t];
        ushort4 v3 = xp4[(size_t)s3 * 96 + t];
        float w0 = sexp[j + 0][h], w1 = sexp[j + 1][h];
        float w2 = sexp[j + 2][h], w3 = sexp[j + 3][h];
        ax = fmaf(w0, b2f(v0.x), ax); ay = fmaf(w0, b2f(v0.y), ay);
        az = fmaf(w0, b2f(v0.z), az); aw = fmaf(w0, b2f(v0.w), aw);
        ax = fmaf(w1, b2f(v1.x), ax); ay = fmaf(w1, b2f(v1.y), ay);
        az = fmaf(w1, b2f(v1.z), az); aw = fmaf(w1, b2f(v1.w), aw);
        ax = fmaf(w2, b2f(v2.x), ax); ay = fmaf(w2, b2f(v2.y), ay);
        az = fmaf(w2, b2f(v2.z), az); aw = fmaf(w2, b2f(v2.w), aw);
        ax = fmaf(w3, b2f(v3.x), ax); ay = fmaf(w3, b2f(v3.y), ay);
        az = fmaf(w3, b2f(v3.z), az); aw = fmaf(w3, b2f(v3.w), aw);
      }
      for (; j < cn; ++j) {
        int s0 = scol[j];
        ushort4 v0 = xp4[(size_t)s0 * 96 + t];
        float w0 = sexp[j][h];
        ax = fmaf(w0, b2f(v0.x), ax); ay = fmaf(w0, b2f(v0.y), ay);
        az = fmaf(w0, b2f(v0.z), az); aw = fmaf(w0, b2f(v0.w), aw);
      }
    }
  }
  if (t < 96) {
    float4 rd = rden4[i];
    float r = (h == 0) ? rd.x : ((h == 1) ? rd.y : rd.z);
    const float4 bg = *(const float4*)(bias_gat + t * 4);
    ushort4 o;
    o.x = f2b(ax * r + bg.x);
    o.y = f2b(ay * r + bg.y);
    o.z = f2b(az * r + bg.z);
    o.w = f2b(aw * r + bg.w);
    *(ushort4*)((unsigned short*)out + (size_t)i * F_ + t * 4) = o;
  }
}

// ---------------- GEMM 4: reduce split-K partials + temp projection ----------------
__global__ __launch_bounds__(128) void temp_kernel(
    const float* __restrict__ Ppart, const float* __restrict__ bproj,
    const float* __restrict__ Wtemp, const float* __restrict__ btemp,
    float* __restrict__ out) {
  int bs = blockIdx.x;          // 0..B*S-1
  int b = bs >> 9;
  int s = bs & (S_ - 1);
  int g = threadIdx.x;
  __shared__ float prow[F_];
  float bp = bproj[s];
  for (int f = g; f < F_; f += 128) {
    float acc = bp;
    const float* pp = Ppart + ((size_t)b * PNS * S_ + s) * F_ + f;
    for (int ns = 0; ns < PNS; ++ns) acc += pp[(size_t)ns * S_ * F_];
    prow[f] = acc;
  }
  __syncthreads();
  float acc = btemp[g];
  const float* w = Wtemp + (size_t)g * F_;
  for (int f = 0; f < F_; f += 4) {
    float4 pv = *(const float4*)&prow[f];
    float4 wv = *(const float4*)&w[f];
    acc += pv.x * wv.x + pv.y * wv.y + pv.z * wv.z + pv.w * wv.w;
  }
  out[(size_t)bs * DG_ + g] = acc;
}

// ---------------- launcher ----------------
extern "C" void kernel_launch(void* const* d_in, const int* in_sizes, int n_in,
                              void* d_out, int out_size, void* d_ws, size_t ws_size,
                              hipStream_t stream) {
  const float* x_enc   = (const float*)d_in[0];
  const float* mask    = (const float*)d_in[1];
  const int*   ei      = (const int*)d_in[2];
  const float* Wq      = (const float*)d_in[3];
  const float* bq      = (const float*)d_in[4];
  const float* Wm      = (const float*)d_in[5];
  const float* bm      = (const float*)d_in[6];
  const float* Wlin    = (const float*)d_in[7];
  const float* att_src = (const float*)d_in[8];
  const float* att_dst = (const float*)d_in[9];
  const float* bias_gat= (const float*)d_in[10];
  const float* Wproj   = (const float*)d_in[11];
  const float* bproj   = (const float*)d_in[12];
  const float* Wtemp   = (const float*)d_in[13];
  const float* btemp   = (const float*)d_in[14];
  float* outp = (float*)d_out;

  char* ws = (char*)d_ws;
  size_t off = 0;
  auto alloc = [&](size_t bytes) {
    char* p = ws + off;
    off = (off + bytes + 255) & ~(size_t)255;
    return p;
  };

  // regionA timeline:
  //   phase 1 (conv/gemm_q/gemm_lin): Wq_b + xeT + xb
  //   phase 2 (agg):                  gat bf16 at 0..30.7M
  //   phase 3 (transpose):            gatT at 31.46..62.2M (reads gat)
  //   phase 4 (gemm_proj):            Ppart fp32 at 0..31.46M (reads gatT)
  const size_t GATT_OFF = 31457536;  // > Ppart end (31,457,280), 256-aligned
  char* regionA = alloc(GATT_OFF + (size_t)B_ * F_ * N_ * 2);   // 62.2 MB
  __hip_bfloat16* Wq_b = (__hip_bfloat16*)regionA;
  __hip_bfloat16* xeT  = (__hip_bfloat16*)(regionA + (size_t)MPADQ * S_ * 2);
  __hip_bfloat16* xb   = (__hip_bfloat16*)(regionA + (size_t)MPADQ * S_ * 2
                                                   + (size_t)B_ * D_ * S_ * 2);
  __hip_bfloat16* gat  = (__hip_bfloat16*)regionA;
  __hip_bfloat16* gatT = (__hip_bfloat16*)(regionA + GATT_OFF);
  float* Ppart = (float*)regionA;

  __hip_bfloat16* xp     = (__hip_bfloat16*)alloc((size_t)BN_ * F_ * 2);
  __hip_bfloat16* WlinB  = (__hip_bfloat16*)alloc((size_t)F_ * D_ * 2);
  __hip_bfloat16* WprojB = (__hip_bfloat16*)alloc((size_t)S_ * N_ * 2);
  float* a_src = (float*)alloc((size_t)BN_ * H_ * 4);
  float* a_dst = (float*)alloc((size_t)BN_ * H_ * 4);
  int* counts  = (int*)alloc((size_t)BN_ * 4);
  int* offsb   = (int*)alloc((size_t)BN_ * 4);
  int* rank    = (int*)alloc((size_t)2 * E_ * 4);
  int* col     = (int*)alloc((size_t)ETOT_ * 4);
  float4* rden4 = (float4*)alloc((size_t)BN_ * 16);
  if (off > ws_size) return;  // workspace too small: fail loudly via absmax

  hipMemsetAsync(counts, 0, (size_t)BN_ * 4, stream);
  // zero the pad rows of xb (rows BN_..MPADL-1) read by gemm_lin A-loads
  hipMemsetAsync(xb + (size_t)BN_ * F_, 0, (size_t)(MPADL - BN_) * F_ * 2, stream);

  // CSR skeleton (independent of everything else)
  count_kernel<<<(2 * E_ + 255) / 256, 256, 0, stream>>>(ei, counts, rank);
  scan_kernel<<<1, 1024, 0, stream>>>(counts, offsb);
  fill_kernel<<<(ETOT_ + 255) / 256, 256, 0, stream>>>(ei, rank, offsb, counts, col);

  // conversions
  conv_wq_kernel<<<(MPADQ * S_ / 4 + 255) / 256, 256, 0, stream>>>(Wq, Wq_b);
  conv_xeT_kernel<<<(B_ * S_ * D_ + 255) / 256, 256, 0, stream>>>(x_enc, xeT);
  conv_bf16_kernel<<<(F_ * D_ / 4 + 255) / 256, 256, 0, stream>>>(Wlin, WlinB, F_ * D_ / 4);
  conv_bf16_kernel<<<(S_ * N_ / 4 + 255) / 256, 256, 0, stream>>>(Wproj, WprojB, S_ * N_ / 4);

  // gemm_q: x[b,n,d] = Wq·xe + bq + mask*Wm + bm   (bf16 MFMA)
  mfma_gemm_nt<1><<<dim3(MPADQ / 128, F_ / 128, B_), 256, 0, stream>>>(
      Wq_b, xeT, xb, S_, N_, (size_t)D_ * S_, (size_t)N_ * F_,
      bq, mask, Wm, bm);
  // gemm_lin: xp = x·Wlin^T   (bf16 MFMA)
  mfma_gemm_nt<0><<<dim3(MPADL / 128, F_ / 128, 1), 256, 0, stream>>>(
      xb, WlinB, xp, D_, BN_, 0, 0, nullptr, nullptr, nullptr, nullptr);

  att_kernel<<<(BN_ * H_ + 3) / 4, 256, 0, stream>>>(xp, att_src, att_dst, a_src, a_dst);
  denom_kernel<<<BN_ / 4, 256, 0, stream>>>(offsb, counts, col, a_src, a_dst, rden4);
  agg_kernel<<<BN_, 128, 0, stream>>>(offsb, counts, col, a_src, a_dst, rden4,
                                      xp, bias_gat, gat);
  transpose_kernel<<<dim3((N_ + TT - 1) / TT, F_ / TT, B_), 256, 0, stream>>>(gat, gatT);
  gemm_proj_mfma<<<dim3(S_ / 128, F_ / 128, B_ * PNS), 256, 0, stream>>>(WprojB, gatT, Ppart);
  temp_kernel<<<B_ * S_, 128, 0, stream>>>(Ppart, bproj, Wtemp, btemp, outp);
}